// Round 16
// baseline (318.606 us; speedup 1.0000x reference)
//
#include <hip/hip_runtime.h>

typedef __attribute__((ext_vector_type(8))) short short8;
typedef __attribute__((ext_vector_type(4))) float f32x4;
typedef unsigned short u16;
typedef unsigned int u32;

__device__ __forceinline__ u16 f2bf(float f) {
  u32 u = __float_as_uint(f);
  u = (u + 0x7fffu + ((u >> 16) & 1u)) >> 16;
  return (u16)u;
}
__device__ __forceinline__ float bf2f(u16 v) { return __uint_as_float((u32)v << 16); }
__device__ __forceinline__ void atomAddF(float* p, float v) { unsafeAtomicAdd(p, v); }
__device__ __forceinline__ void addp(float* v, u32 p) {
  v[0] += bf2f((u16)p);
  v[1] += bf2f((u16)(p >> 16));
}
// order-preserving float<->u32 encode for atomicMax/atomicMin
__device__ __forceinline__ u32 encf(float f) {
  u32 u = __float_as_uint(f);
  return (u & 0x80000000u) ? ~u : (u | 0x80000000u);
}
__device__ __forceinline__ float decf(u32 u) {
  return (u & 0x80000000u) ? __uint_as_float(u ^ 0x80000000u) : __uint_as_float(~u);
}

// ---- prep: pack weights + x->bf16 + bounds + zero scratch + COUNT (deg pre-zeroed
// by hipMemsetAsync) ---- grid E/256
__global__ void prep_k(const float* __restrict__ Wm1, const float* __restrict__ We1,
                       const float* __restrict__ Ws1, const float* __restrict__ Wm2,
                       const float* __restrict__ Wl1, const float* __restrict__ x,
                       const int* __restrict__ batch, const int* __restrict__ ei,
                       u16* __restrict__ Wp1, u16* __restrict__ Wp2,
                       u16* __restrict__ Wp3, u16* __restrict__ xbf,
                       int* __restrict__ gstart, int* __restrict__ gend,
                       int* __restrict__ deg, int* __restrict__ ord,
                       float* __restrict__ bns1p, float* __restrict__ bns2p,
                       float* __restrict__ psumg, u32* __restrict__ pmaxg,
                       u32* __restrict__ pming, int N, int E) {
  int tid = blockIdx.x * 256 + threadIdx.x;
  if (tid < 64 * 192) {  // Wcat1 = [Wm1(16); We1(4); Ws1(16)], pad K to 64
    int k = tid / 192, n = tid % 192;
    float v = 0.f;
    if (k < 16) v = Wm1[k * 192 + n];
    else if (k < 20) v = We1[(k - 16) * 192 + n];
    else if (k < 36) v = Ws1[(k - 20) * 192 + n];
    Wp1[((k >> 3) * 192 + n) * 8 + (k & 7)] = f2bf(v);
  }
  if (tid < 224 * 208) {  // W_msg2, pad K 208->224
    int k = tid / 208, n = tid % 208;
    float v = (k < 208) ? Wm2[k * 208 + n] : 0.f;
    Wp2[((k >> 3) * 208 + n) * 8 + (k & 7)] = f2bf(v);
  }
  if (tid < N * 8) {  // x -> bf16, 2 elems/thread
    float2 p = *(const float2*)(x + (size_t)tid * 2);
    *(u32*)(xbf + (size_t)tid * 2) = (u32)f2bf(p.x) | ((u32)f2bf(p.y) << 16);
  }
  if (tid < N) {
    int b = batch[tid];
    if (tid == 0 || batch[tid - 1] != b) gstart[b] = tid;
    if (tid == N - 1 || batch[tid + 1] != b) gend[b] = tid;
  }
  if (tid < 64 * 384) bns1p[tid] = 0.f;
  if (tid < 64 * 832) bns2p[tid] = 0.f;
  if (tid < 64 * 416) {  // pooled accumulators: sum=0, max=enc(-inf), min=enc(+inf)
    psumg[tid] = 0.f;
    pmaxg[tid] = 0x007FFFFFu;
    pming[tid] = 0xFF800000u;
  }
  if (tid < 1248 * 624) {
    int k = tid / 624, n = tid % 624;
    Wp3[((size_t)(k >> 3) * 624 + n) * 8 + (k & 7)] = f2bf(Wl1[(size_t)k * 624 + n]);
  }
  if (tid < E) {  // count (deg zeroed by memset before this kernel)
    ord[tid] = atomicAdd(&deg[ei[E + tid]], 1);
  }
}

// ---- scan: rowptr = exclusive prefix of deg (fused scanA+scanC) ---- grid nb, 256
__global__ void scan_k(const int* __restrict__ deg, int* __restrict__ rowptr, int N) {
  __shared__ int red[256];
  __shared__ int sh[256];
  int t = threadIdx.x;
  int start = blockIdx.x * 256;
  // block prefix = sum deg[0..start) (redundant per block; L2-resident)
  int acc = 0;
  for (int idx = t; idx < start; idx += 256) acc += deg[idx];
  red[t] = acc;
  __syncthreads();
  for (int off = 128; off > 0; off >>= 1) {
    if (t < off) red[t] += red[t + off];
    __syncthreads();
  }
  int bpref = red[0];
  int i = start + t;
  int d = (i < N) ? deg[i] : 0;
  sh[t] = d;
  __syncthreads();
  for (int off = 1; off < 256; off <<= 1) {
    int u = (t >= off) ? sh[t - off] : 0;
    __syncthreads();
    sh[t] += u;
    __syncthreads();
  }
  int excl = sh[t] - d + bpref;
  if (i < N) {
    rowptr[i] = excl;
    if (i == N - 1) rowptr[N] = excl + d;
  }
}

// ---- scatter (no atomics): se16[rowptr[d]+ord[e]] = {src, ea01, ea23, 0} ----
__global__ void scatter_k(const int* __restrict__ ei, const float* __restrict__ ea,
                          const int* __restrict__ ord, const int* __restrict__ rowptr,
                          int4* __restrict__ se16, int E) {
  int e = blockIdx.x * 256 + threadIdx.x;
  if (e >= E) return;
  int s = ei[e], d = ei[E + e];
  float4 w = *(const float4*)(ea + (size_t)e * 4);
  int slot = rowptr[d] + ord[e];
  int4 ent;
  ent.x = s;
  ent.y = (int)((u32)f2bf(w.x) | ((u32)f2bf(w.y) << 16));
  ent.z = (int)((u32)f2bf(w.z) | ((u32)f2bf(w.w) << 16));
  ent.w = 0;
  se16[slot] = ent;
}

// ---- CONV1: gather1 + U1(LDS) + gemm1 MFMA + h1bf + bn1 stats + h1/x RAW POOLING ----
// grid ceil(N/16), block 256 (4 waves)
__global__ void __launch_bounds__(256) conv1_k(
    const int4* __restrict__ se16, const int* __restrict__ rowptr,
    const u16* __restrict__ xbf, const u16* __restrict__ Bp,
    const float* __restrict__ bm1, const float* __restrict__ be1,
    const float* __restrict__ bs1, u16* __restrict__ acc1c, u16* __restrict__ h1bf,
    float* __restrict__ bns1p, const int* __restrict__ batch,
    float* __restrict__ psumg, u32* __restrict__ pmaxg, u32* __restrict__ pming, int N) {
  __shared__ __align__(16) u16 Uls[16][72];
  __shared__ float degls[16];
  int tid = threadIdx.x;
  int nl = tid >> 4, q = tid & 15;
  int n = blockIdx.x * 16 + nl;
  bool nval = n < N;
  int j0 = nval ? rowptr[n] : 0;
  int j1 = nval ? rowptr[n + 1] : 0;
  int base = blockIdx.x * 16;
  int gid_lo = batch[base];
  int gid_hi = batch[min(base + 15, N - 1)];
  bool uni = (gid_lo == gid_hi);
  float v[20];
#pragma unroll
  for (int i = 0; i < 20; ++i) v[i] = 0.f;
  {
    int j = j0 + q;
    bool a0 = j < j1, a1 = (j + 16) < j1;
    int jj0 = a0 ? j : 0;
    int jj1 = a1 ? (j + 16) : 0;
    int4 p0 = se16[jj0];
    int4 p1 = se16[jj1];
    const uint4* xs0 = (const uint4*)(xbf + (size_t)(a0 ? p0.x : 0) * 16);
    uint4 x00 = xs0[0], x01 = xs0[1];
    const uint4* xs1 = (const uint4*)(xbf + (size_t)(a1 ? p1.x : 0) * 16);
    uint4 x10 = xs1[0], x11 = xs1[1];
    if (a0) {
      addp(v + 0, x00.x); addp(v + 2, x00.y); addp(v + 4, x00.z); addp(v + 6, x00.w);
      addp(v + 8, x01.x); addp(v + 10, x01.y); addp(v + 12, x01.z); addp(v + 14, x01.w);
      addp(v + 16, (u32)p0.y); addp(v + 18, (u32)p0.z);
    }
    if (a1) {
      addp(v + 0, x10.x); addp(v + 2, x10.y); addp(v + 4, x10.z); addp(v + 6, x10.w);
      addp(v + 8, x11.x); addp(v + 10, x11.y); addp(v + 12, x11.z); addp(v + 14, x11.w);
      addp(v + 16, (u32)p1.y); addp(v + 18, (u32)p1.z);
    }
    for (j += 32; j < j1; j += 16) {  // rare tail (deg > 32)
      int4 p = se16[j];
      const uint4* xs = (const uint4*)(xbf + (size_t)p.x * 16);
      uint4 x0 = xs[0], x1 = xs[1];
      addp(v + 0, x0.x); addp(v + 2, x0.y); addp(v + 4, x0.z); addp(v + 6, x0.w);
      addp(v + 8, x1.x); addp(v + 10, x1.y); addp(v + 12, x1.z); addp(v + 14, x1.w);
      addp(v + 16, (u32)p.y); addp(v + 18, (u32)p.z);
    }
  }
#pragma unroll
  for (int i = 0; i < 20; ++i) {
    v[i] += __shfl_xor(v[i], 1);
    v[i] += __shfl_xor(v[i], 2);
    v[i] += __shfl_xor(v[i], 4);
    v[i] += __shfl_xor(v[i], 8);
  }
  float degf = (float)(j1 - j0);
  const u16* xr = xbf + (size_t)n * 16;
  {  // U1 row -> LDS: [sums20, x(n)16, 0..]; lane q writes elems q*4..q*4+3
    u32 w2[2];
#pragma unroll
    for (int jj = 0; jj < 2; ++jj) {
      int t0 = q * 4 + 2 * jj, t1 = t0 + 1;
      u16 b0 = (t0 < 20) ? f2bf(v[t0]) : ((t0 < 36 && nval) ? xr[t0 - 20] : (u16)0);
      u16 b1 = (t1 < 20) ? f2bf(v[t1]) : ((t1 < 36 && nval) ? xr[t1 - 20] : (u16)0);
      w2[jj] = (u32)b0 | ((u32)b1 << 16);
    }
    *(uint2*)&Uls[nl][q * 4] = make_uint2(w2[0], w2[1]);
  }
  if (nval) {  // acc1c row: [sx16, sea4, deg, 0..]; lane q -> elems 2q,2q+1
    int t0 = q * 2, t1 = t0 + 1;
    float f0 = (t0 < 20) ? v[t0] : ((t0 == 20) ? degf : 0.f);
    float f1 = (t1 < 20) ? v[t1] : ((t1 == 20) ? degf : 0.f);
    *(u32*)(acc1c + (size_t)n * 32 + q * 2) = (u32)f2bf(f0) | ((u32)f2bf(f1) << 16);
  }
  if (q == 0) degls[nl] = degf;
  __syncthreads();
  // Phase B: 12 n-tile jobs over 4 waves; h1 raw pooling fused (f = 208+col)
  int w = tid >> 6, lane = tid & 63, rc = lane & 15, qd = lane >> 4;
  int slice = (blockIdx.x & 63) * 384;
  for (int nt = w; nt < 12; nt += 4) {
    f32x4 acc = {0.f, 0.f, 0.f, 0.f};
#pragma unroll
    for (int kb = 0; kb < 2; ++kb) {
      short8 av = *(const short8*)&Uls[rc][kb * 32 + qd * 8];
      short8 bv = *(const short8*)(Bp + (size_t)((kb * 4 + qd) * 192 + nt * 16 + rc) * 8);
      acc = __builtin_amdgcn_mfma_f32_16x16x32_bf16(av, bv, acc, 0, 0, 0);
    }
    int col = nt * 16 + rc;
    float bb = bm1[col] + be1[col], bsv = bs1[col];
    float ps = 0.f, pq = 0.f;
    float sl = 0.f, mxl = -3.4e38f, mnl = 3.4e38f;
    float vv[4];
#pragma unroll
    for (int r = 0; r < 4; ++r) {
      int ml = qd * 4 + r;
      int m = blockIdx.x * 16 + ml;
      float val = acc[r] + degls[ml] * bb + bsv;
      u16 vb = f2bf(val);
      float vr = bf2f(vb);  // pooled value = bf16-rounded (matches h1bf read)
      vv[r] = vr;
      if (m < N) {
        h1bf[(size_t)m * 192 + col] = vb;
        ps += val;
        pq += val * val;
        sl += vr;
        mxl = fmaxf(mxl, vr);
        mnl = fminf(mnl, vr);
      }
    }
    ps += __shfl_xor(ps, 16); ps += __shfl_xor(ps, 32);
    pq += __shfl_xor(pq, 16); pq += __shfl_xor(pq, 32);
    if (uni) {
      sl += __shfl_xor(sl, 16); sl += __shfl_xor(sl, 32);
      mxl = fmaxf(mxl, __shfl_xor(mxl, 16)); mxl = fmaxf(mxl, __shfl_xor(mxl, 32));
      mnl = fminf(mnl, __shfl_xor(mnl, 16)); mnl = fminf(mnl, __shfl_xor(mnl, 32));
    }
    if (qd == 0) {
      atomAddF(&bns1p[slice + col], ps);
      atomAddF(&bns1p[slice + 192 + col], pq);
      if (uni) {
        int pidx = gid_lo * 416 + 208 + col;
        atomAddF(&psumg[pidx], sl);
        atomicMax(&pmaxg[pidx], encf(mxl));
        atomicMin(&pming[pidx], encf(mnl));
      }
    }
    if (!uni) {  // boundary block: per-run atomics over this lane's 4 rows
      int cg = -1;
      float rs = 0.f, rmx = -3.4e38f, rmn = 3.4e38f;
#pragma unroll
      for (int r = 0; r < 4; ++r) {
        int m = blockIdx.x * 16 + qd * 4 + r;
        if (m >= N) continue;
        int g = batch[m];
        if (g != cg) {
          if (cg >= 0) {
            int pidx = cg * 416 + 208 + col;
            atomAddF(&psumg[pidx], rs);
            atomicMax(&pmaxg[pidx], encf(rmx));
            atomicMin(&pming[pidx], encf(rmn));
          }
          cg = g; rs = 0.f; rmx = -3.4e38f; rmn = 3.4e38f;
        }
        rs += vv[r];
        rmx = fmaxf(rmx, vv[r]);
        rmn = fminf(rmn, vv[r]);
      }
      if (cg >= 0) {
        int pidx = cg * 416 + 208 + col;
        atomAddF(&psumg[pidx], rs);
        atomicMax(&pmaxg[pidx], encf(rmx));
        atomicMin(&pming[pidx], encf(rmn));
      }
    }
  }
  // ---- pool x from Uls cols 20..35 (raw): -> global feature 400+c, c in [0,16) ----
  if (tid < 16) {
    int c = tid;
    int rows = min(16, N - base);
    if (uni) {
      float s = 0.f, mx = -3.4e38f, mn = 3.4e38f;
      for (int ml = 0; ml < rows; ++ml) {
        float vx = bf2f(Uls[ml][20 + c]);
        s += vx;
        mx = fmaxf(mx, vx);
        mn = fminf(mn, vx);
      }
      int pidx = gid_lo * 416 + 400 + c;
      atomAddF(&psumg[pidx], s);
      atomicMax(&pmaxg[pidx], encf(mx));
      atomicMin(&pming[pidx], encf(mn));
    } else {
      int cg = -1;
      float rs = 0.f, rmx = -3.4e38f, rmn = 3.4e38f;
      for (int ml = 0; ml < rows; ++ml) {
        int g = batch[base + ml];
        if (g != cg) {
          if (cg >= 0) {
            int pidx = cg * 416 + 400 + c;
            atomAddF(&psumg[pidx], rs);
            atomicMax(&pmaxg[pidx], encf(rmx));
            atomicMin(&pming[pidx], encf(rmn));
          }
          cg = g; rs = 0.f; rmx = -3.4e38f; rmn = 3.4e38f;
        }
        float vx = bf2f(Uls[ml][20 + c]);
        rs += vx;
        rmx = fmaxf(rmx, vx);
        rmn = fminf(rmn, vx);
      }
      if (cg >= 0) {
        int pidx = cg * 416 + 400 + c;
        atomAddF(&psumg[pidx], rs);
        atomicMax(&pmaxg[pidx], encf(rmx));
        atomicMin(&pming[pidx], encf(rmn));
      }
    }
  }
}

// ---- bn1 finalize ---- 1 block, 256 threads
__global__ void bnfin1_k(const float* __restrict__ bns1p, const float* __restrict__ g1,
                         const float* __restrict__ bta1, float Ninv,
                         float* __restrict__ aff1) {
  int c = threadIdx.x;
  if (c >= 192) return;
  float sm = 0.f, sq = 0.f;
  for (int k = 0; k < 64; ++k) {
    sm += bns1p[k * 384 + c];
    sq += bns1p[k * 384 + 192 + c];
  }
  float m1 = sm * Ninv;
  float var = sq * Ninv - m1 * m1;
  float s1 = g1[c] * rsqrtf(var + 1e-5f);
  aff1[c] = s1;
  aff1[192 + c] = bta1[c] - m1 * s1;
}

// ---- CONV2: gather2 + U2 + X1 staged + gemms + bn2 stats + h2 RAW POOLING only ----
// grid ceil(N/16), block 256 (4 waves). h2 never materialized.
__global__ void __launch_bounds__(256) conv2_k(
    const int4* __restrict__ se16, const int* __restrict__ rowptr,
    const u16* __restrict__ acc1c, const u16* __restrict__ h1bf,
    const u16* __restrict__ xbf, const u16* __restrict__ Bp1, const u16* __restrict__ Bp2,
    const float* __restrict__ bm1, const float* __restrict__ be1,
    const float* __restrict__ bs1, const float* __restrict__ aff1,
    const float* __restrict__ We2, const float* __restrict__ bm2,
    const float* __restrict__ be2, float* __restrict__ bns2p,
    const int* __restrict__ batch, float* __restrict__ psumg,
    u32* __restrict__ pmaxg, u32* __restrict__ pming, int N) {
  __shared__ __align__(16) u16 Uls[16][72];
  __shared__ __align__(16) u16 Vls[16][232];
  __shared__ __align__(16) u16 X1ls[16][208];  // cols 0..191 h1 raw, 192..207 x raw
  __shared__ float degls[16], sdegls[16], eals[16][4];
  int tid = threadIdx.x;
  int nl = tid >> 4, q = tid & 15;
  int n = blockIdx.x * 16 + nl;
  bool nval = n < N;
  int j0 = nval ? rowptr[n] : 0;
  int j1 = nval ? rowptr[n + 1] : 0;
  int base = blockIdx.x * 16;
  int gid_lo = batch[base];
  int gid_hi = batch[min(base + 15, N - 1)];
  bool uni = (gid_lo == gid_hi);

  // ---- stage X1 rows: issue coalesced loads first (overlap with gather) ----
  uint4 sg0, sg1, sgx;
  int r0 = tid / 24, c0 = tid % 24;                 // rows 0..10
  int r1 = (tid + 256) / 24, c1 = (tid + 256) % 24; // rows 10..15 (tid<128)
  {
    int gr = base + r0;
    sg0 = (gr < N) ? *(const uint4*)(h1bf + (size_t)gr * 192 + c0 * 8)
                   : make_uint4(0, 0, 0, 0);
  }
  if (tid < 128) {
    int gr = base + r1;
    sg1 = (gr < N) ? *(const uint4*)(h1bf + (size_t)gr * 192 + c1 * 8)
                   : make_uint4(0, 0, 0, 0);
  }
  if (tid < 32) {
    int gr = base + (tid >> 1);
    sgx = (gr < N) ? *(const uint4*)(xbf + (size_t)gr * 16 + (tid & 1) * 8)
                   : make_uint4(0, 0, 0, 0);
  }

  float v[21];
#pragma unroll
  for (int i = 0; i < 21; ++i) v[i] = 0.f;
  {
    // Unrolled 2-deep gather prefetch (see conv1_k).
    int j = j0 + q;
    bool a0 = j < j1, a1 = (j + 16) < j1;
    int jj0 = a0 ? j : 0;
    int jj1 = a1 ? (j + 16) : 0;
    int4 p0 = se16[jj0];
    int4 p1 = se16[jj1];
    const uint4* cr0 = (const uint4*)(acc1c + (size_t)(a0 ? p0.x : 0) * 32);
    uint4 c00 = cr0[0], c01 = cr0[1], c02 = cr0[2];
    const uint4* cr1 = (const uint4*)(acc1c + (size_t)(a1 ? p1.x : 0) * 32);
    uint4 c10 = cr1[0], c11 = cr1[1], c12 = cr1[2];
    if (a0) {
      addp(v + 0, c00.x); addp(v + 2, c00.y); addp(v + 4, c00.z); addp(v + 6, c00.w);
      addp(v + 8, c01.x); addp(v + 10, c01.y); addp(v + 12, c01.z); addp(v + 14, c01.w);
      addp(v + 16, c02.x); addp(v + 18, c02.y);
      v[20] += bf2f((u16)c02.z);
    }
    if (a1) {
      addp(v + 0, c10.x); addp(v + 2, c10.y); addp(v + 4, c10.z); addp(v + 6, c10.w);
      addp(v + 8, c11.x); addp(v + 10, c11.y); addp(v + 12, c11.z); addp(v + 14, c11.w);
      addp(v + 16, c12.x); addp(v + 18, c12.y);
      v[20] += bf2f((u16)c12.z);
    }
    for (j += 32; j < j1; j += 16) {  // rare tail (deg > 32)
      int s = se16[j].x;
      const uint4* cr = (const uint4*)(acc1c + (size_t)s * 32);
      uint4 c0 = cr[0], c1 = cr[1], c2 = cr[2];
      addp(v + 0, c0.x); addp(v + 2, c0.y); addp(v + 4, c0.z); addp(v + 6, c0.w);
      addp(v + 8, c1.x); addp(v + 10, c1.y); addp(v + 12, c1.z); addp(v + 14, c1.w);
      addp(v + 16, c2.x); addp(v + 18, c2.y);
      v[20] += bf2f((u16)c2.z);
    }
  }

  // ---- write staged X1 rows to LDS (loads had gather-time to land) ----
  *(uint4*)&X1ls[r0][c0 * 8] = sg0;
  if (tid < 128) *(uint4*)&X1ls[r1][c1 * 8] = sg1;
  if (tid < 32) *(uint4*)&X1ls[tid >> 1][192 + (tid & 1) * 8] = sgx;

#pragma unroll
  for (int i = 0; i < 21; ++i) {
    v[i] += __shfl_xor(v[i], 1);
    v[i] += __shfl_xor(v[i], 2);
    v[i] += __shfl_xor(v[i], 4);
    v[i] += __shfl_xor(v[i], 8);
  }
  const u16* selfr = acc1c + (size_t)n * 32;
  {  // U2 row -> LDS: [sums20, self sx16, 0..]; lane q writes elems q*4..q*4+3
    u32 w2[2];
#pragma unroll
    for (int jj = 0; jj < 2; ++jj) {
      int t0 = q * 4 + 2 * jj, t1 = t0 + 1;
      u16 b0 = (t0 < 20) ? f2bf(v[t0]) : ((t0 < 36 && nval) ? selfr[t0 - 20] : (u16)0);
      u16 b1 = (t1 < 20) ? f2bf(v[t1]) : ((t1 < 36 && nval) ? selfr[t1 - 20] : (u16)0);
      w2[jj] = (u32)b0 | ((u32)b1 << 16);
    }
    *(uint2*)&Uls[nl][q * 4] = make_uint2(w2[0], w2[1]);
  }
  {  // V tail cols [192..224): self sx16 then zeros; lane q -> elems 192+2q, +1
    int t0 = q * 2, t1 = t0 + 1;
    u16 b0 = (t0 < 16 && nval) ? selfr[t0] : (u16)0;
    u16 b1 = (t1 < 16 && nval) ? selfr[t1] : (u16)0;
    *(u32*)&Vls[nl][192 + q * 2] = (u32)b0 | ((u32)b1 << 16);
  }
  if (q == 0) sdegls[nl] = v[20];
  if (q == 1) degls[nl] = nval ? bf2f(selfr[20]) : 0.f;
  if (q == 2) {
#pragma unroll
    for (int k = 0; k < 4; ++k) eals[nl][k] = nval ? bf2f(selfr[16 + k]) : 0.f;
  }
  __syncthreads();
  // Phase B: gemmq2 -> Vls[:,0..192), 12 jobs / 4 waves
  int w = tid >> 6, lane = tid & 63, rc = lane & 15, qd = lane >> 4;
  for (int nt = w; nt < 12; nt += 4) {
    f32x4 acc = {0.f, 0.f, 0.f, 0.f};
#pragma unroll
    for (int kb = 0; kb < 2; ++kb) {
      short8 av = *(const short8*)&Uls[rc][kb * 32 + qd * 8];
      short8 bv = *(const short8*)(Bp1 + (size_t)((kb * 4 + qd) * 192 + nt * 16 + rc) * 8);
      acc = __builtin_amdgcn_mfma_f32_16x16x32_bf16(av, bv, acc, 0, 0, 0);
    }
    int col = nt * 16 + rc;
    float s1 = aff1[col], t1 = aff1[192 + col];
    float bb = bm1[col] + be1[col], bsv = bs1[col];
#pragma unroll
    for (int r = 0; r < 4; ++r) {
      int ml = qd * 4 + r;
      float qv = acc[r] + sdegls[ml] * bb + degls[ml] * bsv;
      Vls[ml][col] = f2bf(qv * s1 + degls[ml] * t1);
    }
  }
  __syncthreads();
  // Phase C: gemm2 + bn2 stats + h2 pooling (raw); NO h2 store at all.
  int slice = (blockIdx.x & 63) * 832;
  for (int nt = w; nt < 13; nt += 4) {
    f32x4 acc = {0.f, 0.f, 0.f, 0.f};
#pragma unroll
    for (int kb = 0; kb < 7; ++kb) {
      short8 av = *(const short8*)&Vls[rc][kb * 32 + qd * 8];
      short8 bv = *(const short8*)(Bp2 + (size_t)((kb * 4 + qd) * 208 + nt * 16 + rc) * 8);
      acc = __builtin_amdgcn_mfma_f32_16x16x32_bf16(av, bv, acc, 0, 0, 0);
    }
    int col = nt * 16 + rc;
    float w0 = We2[col], w1 = We2[208 + col], w2 = We2[416 + col], w3 = We2[624 + col];
    float bb2 = bm2[col] + be2[col];
    bool c192 = col < 192;
    float s1 = c192 ? aff1[col] : 0.f;
    float t1 = c192 ? aff1[192 + col] : 0.f;
    float ps = 0.f, pq = 0.f;
    float sl = 0.f, mxl = -3.4e38f, mnl = 3.4e38f;
    float vv[4];
#pragma unroll
    for (int r = 0; r < 4; ++r) {
      int ml = qd * 4 + r;
      int m = blockIdx.x * 16 + ml;
      bool mv = m < N;
      float x1 = bf2f(X1ls[ml][col]);
      if (c192) x1 = x1 * s1 + t1;
      float val = acc[r] + eals[ml][0] * w0 + eals[ml][1] * w1 + eals[ml][2] * w2 +
                  eals[ml][3] * w3 + degls[ml] * bb2 + x1;
      vv[r] = val;
      if (mv) {
        ps += val;
        pq += val * val;
        sl += val;
        mxl = fmaxf(mxl, val);
        mnl = fminf(mnl, val);
      }
    }
    ps += __shfl_xor(ps, 16); ps += __shfl_xor(ps, 32);
    pq += __shfl_xor(pq, 16); pq += __shfl_xor(pq, 32);
    if (uni) {
      sl += __shfl_xor(sl, 16); sl += __shfl_xor(sl, 32);
      mxl = fmaxf(mxl, __shfl_xor(mxl, 16)); mxl = fmaxf(mxl, __shfl_xor(mxl, 32));
      mnl = fminf(mnl, __shfl_xor(mnl, 16)); mnl = fminf(mnl, __shfl_xor(mnl, 32));
    }
    if (qd == 0) {
      atomAddF(&bns2p[slice + col], ps);
      atomAddF(&bns2p[slice + 416 + col], pq);
      if (uni) {
        int pidx = gid_lo * 416 + col;
        atomAddF(&psumg[pidx], sl);
        atomicMax(&pmaxg[pidx], encf(mxl));
        atomicMin(&pming[pidx], encf(mnl));
      }
    }
    if (!uni) {  // boundary block (~4%): per-run atomics over this lane's 4 rows
      int cg = -1;
      float rs = 0.f, rmx = -3.4e38f, rmn = 3.4e38f;
#pragma unroll
      for (int r = 0; r < 4; ++r) {
        int m = blockIdx.x * 16 + qd * 4 + r;
        if (m >= N) continue;
        int g = batch[m];
        if (g != cg) {
          if (cg >= 0) {
            int pidx = cg * 416 + col;
            atomAddF(&psumg[pidx], rs);
            atomicMax(&pmaxg[pidx], encf(rmx));
            atomicMin(&pming[pidx], encf(rmn));
          }
          cg = g; rs = 0.f; rmx = -3.4e38f; rmn = 3.4e38f;
        }
        rs += vv[r];
        rmx = fmaxf(rmx, vv[r]);
        rmn = fminf(rmn, vv[r]);
      }
      if (cg >= 0) {
        int pidx = cg * 416 + col;
        atomAddF(&psumg[pidx], rs);
        atomicMax(&pmaxg[pidx], encf(rmx));
        atomicMin(&pming[pidx], encf(rmn));
      }
    }
  }
}

// ---- MLP layer 1: pooled A built in LDS (pooledprep folded) + MFMA, K/4 waves ----
// grid=(4,39), block 256
__global__ void __launch_bounds__(256) mlpgemm_k(
    const float* __restrict__ psumg, const u32* __restrict__ pmaxg,
    const u32* __restrict__ pming, const int* __restrict__ gstart,
    const int* __restrict__ gend, const float* __restrict__ bns2p,
    const float* __restrict__ aff1, const float* __restrict__ g2,
    const float* __restrict__ bta2, float Ninv, const u16* __restrict__ Bp,
    const float* __restrict__ b1, const float* __restrict__ al,
    float* __restrict__ hid) {
  __shared__ float scs[416], shs[416];
  __shared__ __align__(16) u16 Als[16][1256];  // stride-padded (1256) vs 1248
  __shared__ __align__(16) float part[3][64][4];
  int tid = threadIdx.x;
  int mt = blockIdx.x, nt = blockIdx.y;
  // phase 0: bn affines (bns2p L2-resident; 156 blocks redundant = cheap)
  for (int f = tid; f < 416; f += 256) {
    float sc, sh;
    if (f < 208) {
      float sm = 0.f, sq = 0.f;
      for (int k = 0; k < 64; ++k) {
        sm += bns2p[k * 832 + f];
        sq += bns2p[k * 832 + 416 + f];
      }
      float m2 = sm * Ninv;
      float var = sq * Ninv - m2 * m2;
      sc = g2[f] * rsqrtf(var + 1e-5f);
      sh = bta2[f] - m2 * sc;
    } else if (f < 400) {
      sc = aff1[f - 208];
      sh = aff1[192 + (f - 208)];
    } else {
      sc = 1.f;
      sh = 0.f;
    }
    scs[f] = sc;
    shs[f] = sh;
  }
  __syncthreads();
  // phase 1: build 16 A-rows (graphs mt*16..mt*16+15) in LDS
  for (int e = tid; e < 16 * 416; e += 256) {
    int g = e / 416, f = e % 416;
    int b = mt * 16 + g;
    int cnt = gend[b] - gstart[b] + 1;
    float inv = 1.f / (float)max(cnt, 1);
    float s = psumg[b * 416 + f];
    float mx = decf(pmaxg[b * 416 + f]);
    float mn = decf(pming[b * 416 + f]);
    float sc = scs[f], sh = shs[f];
    float sumf = sc * s + (float)cnt * sh;
    float mxf = (sc >= 0.f) ? sc * mx + sh : sc * mn + sh;
    Als[g][f] = f2bf(sumf);
    Als[g][416 + f] = f2bf((cnt > 0) ? mxf : 0.f);
    Als[g][832 + f] = f2bf(sumf * inv);
  }
  __syncthreads();
  // phase 2: MFMA, K split over 4 waves + LDS reduce
  int w = tid >> 6, lane = tid & 63;
  int rc = lane & 15, qd = lane >> 4;
  f32x4 acc = {0.f, 0.f, 0.f, 0.f};
  const u16* Bq = Bp + (size_t)(qd * 624 + nt * 16 + rc) * 8;
  for (int kb = w; kb < 39; kb += 4) {
    short8 av = *(const short8*)&Als[rc][kb * 32 + qd * 8];
    short8 bv = *(const short8*)(Bq + (size_t)kb * 4 * 624 * 8);
    acc = __builtin_amdgcn_mfma_f32_16x16x32_bf16(av, bv, acc, 0, 0, 0);
  }
  if (w > 0) *(f32x4*)&part[w - 1][lane][0] = acc;
  __syncthreads();
  if (w == 0) {
#pragma unroll
    for (int j = 0; j < 3; ++j) {
      f32x4 p = *(const f32x4*)&part[j][lane][0];
      acc[0] += p[0]; acc[1] += p[1]; acc[2] += p[2]; acc[3] += p[3];
    }
    int col = nt * 16 + rc;
    float bb = b1[col], alpha = al[0];
    int m0 = mt * 16 + qd * 4;
#pragma unroll
    for (int r = 0; r < 4; ++r) {
      float v = acc[r] + bb;
      hid[(size_t)(m0 + r) * 624 + col] = (v >= 0.f) ? v : alpha * v;
    }
  }
}

// ---- logits + log_softmax ---- grid=64, block=64
__global__ void head_k(const float* __restrict__ hid, const float* __restrict__ W2,
                       const float* __restrict__ b2, float* __restrict__ out) {
  int b = blockIdx.x, t = threadIdx.x;
  float p0 = 0.f, p1 = 0.f;
  for (int k = t; k < 624; k += 64) {
    float h = hid[(size_t)b * 624 + k];
    p0 += h * W2[k * 2];
    p1 += h * W2[k * 2 + 1];
  }
#pragma unroll
  for (int off = 32; off > 0; off >>= 1) {
    p0 += __shfl_down(p0, off);
    p1 += __shfl_down(p1, off);
  }
  if (t == 0) {
    float l0 = p0 + b2[0], l1 = p1 + b2[1];
    float m = fmaxf(l0, l1);
    float lse = m + logf(expf(l0 - m) + expf(l1 - m));
    out[b * 2] = l0 - lse;
    out[b * 2 + 1] = l1 - lse;
  }
}

extern "C" void kernel_launch(void* const* d_in, const int* in_sizes, int n_in,
                              void* d_out, int out_size, void* d_ws, size_t ws_size,
                              hipStream_t stream) {
  const float* x = (const float*)d_in[0];
  const int* ei = (const int*)d_in[1];
  const float* ea = (const float*)d_in[2];
  const int* batch = (const int*)d_in[3];
  const float* Wm1 = (const float*)d_in[4];
  const float* bm1 = (const float*)d_in[5];
  const float* We1 = (const float*)d_in[6];
  const float* be1 = (const float*)d_in[7];
  const float* Ws1 = (const float*)d_in[8];
  const float* bs1 = (const float*)d_in[9];
  const float* g1 = (const float*)d_in[10];
  const float* bta1 = (const float*)d_in[11];
  const float* Wm2 = (const float*)d_in[12];
  const float* bm2 = (const float*)d_in[13];
  const float* We2 = (const float*)d_in[14];
  const float* be2 = (const float*)d_in[15];
  const float* g2 = (const float*)d_in[16];
  const float* bta2 = (const float*)d_in[17];
  const float* Wl1 = (const float*)d_in[18];
  const float* bl1 = (const float*)d_in[19];
  const float* alpha = (const float*)d_in[20];
  const float* Wl2 = (const float*)d_in[21];
  const float* bl2 = (const float*)d_in[22];
  float* out = (float*)d_out;

  const int N = in_sizes[3];      // 50000
  const int E = in_sizes[2] / 4;  // 800000
  const int nb = (N + 255) / 256; // 196 (<=256)
  const float Ninv = 1.f / (float)N;

  float* ws = (float*)d_ws;
  size_t o = 0;
  u16* acc1c = (u16*)(ws + o); o += (size_t)N * 16;  // N*32 u16
  u16* h1bf = (u16*)(ws + o);  o += (size_t)N * 96;  // N*192 u16
  u16* xbf = (u16*)(ws + o);   o += (size_t)N * 8;   // N*16 u16
  u16* Wp1 = (u16*)(ws + o);   o += 6144;
  u16* Wp2 = (u16*)(ws + o);   o += 23296;
  u16* Wp3 = (u16*)(ws + o);   o += 389376;
  float* hid = ws + o;    o += 64 * 624;
  float* bns1p = ws + o;  o += 64 * 384;
  float* bns2p = ws + o;  o += 64 * 832;
  float* aff1 = ws + o;   o += 384;
  float* psumg = ws + o;  o += 64 * 416;
  u32* pmaxg = (u32*)(ws + o); o += 64 * 416;
  u32* pming = (u32*)(ws + o); o += 64 * 416;
  int* gstart = (int*)(ws + o); o += 64;
  int* gend = (int*)(ws + o);   o += 64;
  int* deg = (int*)(ws + o);    o += N;
  int* rowptr = (int*)(ws + o); o += N + 1;
  int* ord = (int*)(ws + o);    o += E;
  o = (o + 3) & ~(size_t)3;  // 16B align for int4
  int4* se16 = (int4*)(ws + o); o += (size_t)4 * E;

  const int gconv = (N + 15) / 16;  // 3125
  hipMemsetAsync(deg, 0, (size_t)N * sizeof(int), stream);
  prep_k<<<(E + 255) / 256, 256, 0, stream>>>(Wm1, We1, Ws1, Wm2, Wl1, x, batch, ei,
                                              Wp1, Wp2, Wp3, xbf, gstart, gend, deg,
                                              ord, bns1p, bns2p, psumg, pmaxg, pming,
                                              N, E);
  scan_k<<<nb, 256, 0, stream>>>(deg, rowptr, N);
  scatter_k<<<(E + 255) / 256, 256, 0, stream>>>(ei, ea, ord, rowptr, se16, E);
  conv1_k<<<gconv, 256, 0, stream>>>(se16, rowptr, xbf, Wp1, bm1, be1, bs1, acc1c, h1bf,
                                     bns1p, batch, psumg, pmaxg, pming, N);
  bnfin1_k<<<1, 256, 0, stream>>>(bns1p, g1, bta1, Ninv, aff1);
  conv2_k<<<gconv, 256, 0, stream>>>(se16, rowptr, acc1c, h1bf, xbf, Wp1, Wp2, bm1, be1,
                                     bs1, aff1, We2, bm2, be2, bns2p, batch, psumg,
                                     pmaxg, pming, N);
  mlpgemm_k<<<dim3(4, 39), 256, 0, stream>>>(psumg, pmaxg, pming, gstart, gend, bns2p,
                                             aff1, g2, bta2, Ninv, Wp3, bl1, alpha, hid);
  head_k<<<64, 64, 0, stream>>>(hid, Wl2, bl2, out);
}

// Round 17
// 310.997 us; speedup vs baseline: 1.0245x; 1.0245x over previous
//
#include <hip/hip_runtime.h>

typedef __attribute__((ext_vector_type(8))) short short8;
typedef __attribute__((ext_vector_type(4))) float f32x4;
typedef unsigned short u16;
typedef unsigned int u32;

__device__ __forceinline__ u16 f2bf(float f) {
  u32 u = __float_as_uint(f);
  u = (u + 0x7fffu + ((u >> 16) & 1u)) >> 16;
  return (u16)u;
}
__device__ __forceinline__ float bf2f(u16 v) { return __uint_as_float((u32)v << 16); }
__device__ __forceinline__ void atomAddF(float* p, float v) { unsafeAtomicAdd(p, v); }
__device__ __forceinline__ void addp(float* v, u32 p) {
  v[0] += bf2f((u16)p);
  v[1] += bf2f((u16)(p >> 16));
}
// order-preserving float<->u32 encode for atomicMax/atomicMin
__device__ __forceinline__ u32 encf(float f) {
  u32 u = __float_as_uint(f);
  return (u & 0x80000000u) ? ~u : (u | 0x80000000u);
}
__device__ __forceinline__ float decf(u32 u) {
  return (u & 0x80000000u) ? __uint_as_float(u ^ 0x80000000u) : __uint_as_float(~u);
}

// ---- prep: pack bf16 weights + x->bf16 + graph bounds + zero scratch ---- grid E/256
__global__ void prep_k(const float* __restrict__ Wm1, const float* __restrict__ We1,
                       const float* __restrict__ Ws1, const float* __restrict__ Wm2,
                       const float* __restrict__ Wl1, const float* __restrict__ x,
                       const int* __restrict__ batch, u16* __restrict__ Wp1,
                       u16* __restrict__ Wp2, u16* __restrict__ Wp3,
                       u16* __restrict__ xbf, int* __restrict__ gstart,
                       int* __restrict__ gend, int* __restrict__ deg,
                       float* __restrict__ bns1p, float* __restrict__ bns2p,
                       float* __restrict__ psumg, u32* __restrict__ pmaxg,
                       u32* __restrict__ pming, int N, int E) {
  int tid = blockIdx.x * 256 + threadIdx.x;
  if (tid < 64 * 192) {  // Wcat1 = [Wm1(16); We1(4); Ws1(16)], pad K to 64
    int k = tid / 192, n = tid % 192;
    float v = 0.f;
    if (k < 16) v = Wm1[k * 192 + n];
    else if (k < 20) v = We1[(k - 16) * 192 + n];
    else if (k < 36) v = Ws1[(k - 20) * 192 + n];
    Wp1[((k >> 3) * 192 + n) * 8 + (k & 7)] = f2bf(v);
  }
  if (tid < 224 * 208) {  // W_msg2, pad K 208->224
    int k = tid / 208, n = tid % 208;
    float v = (k < 208) ? Wm2[k * 208 + n] : 0.f;
    Wp2[((k >> 3) * 208 + n) * 8 + (k & 7)] = f2bf(v);
  }
  if (tid < N * 8) {  // x -> bf16, 2 elems/thread
    float2 p = *(const float2*)(x + (size_t)tid * 2);
    *(u32*)(xbf + (size_t)tid * 2) = (u32)f2bf(p.x) | ((u32)f2bf(p.y) << 16);
  }
  if (tid < N) {
    int b = batch[tid];
    if (tid == 0 || batch[tid - 1] != b) gstart[b] = tid;
    if (tid == N - 1 || batch[tid + 1] != b) gend[b] = tid;
    deg[tid] = 0;
  }
  if (tid < 64 * 384) bns1p[tid] = 0.f;
  if (tid < 64 * 832) bns2p[tid] = 0.f;
  if (tid < 64 * 416) {  // pooled accumulators: sum=0, max=enc(-inf), min=enc(+inf)
    psumg[tid] = 0.f;
    pmaxg[tid] = 0x007FFFFFu;
    pming[tid] = 0xFF800000u;
  }
  if (tid < 1248 * 624) {
    int k = tid / 624, n = tid % 624;
    Wp3[((size_t)(k >> 3) * 624 + n) * 8 + (k & 7)] = f2bf(Wl1[(size_t)k * 624 + n]);
  }
}

// ---- count + within-row ordinal (separate kernel: fusing into prep_k regressed
// prep 15->66us, R16 evidence) ----
__global__ void count_k(const int* __restrict__ ei, int* __restrict__ deg,
                        int* __restrict__ ord, int E) {
  int e = blockIdx.x * 256 + threadIdx.x;
  if (e >= E) return;
  ord[e] = atomicAdd(&deg[ei[E + e]], 1);
}

// ---- scan: rowptr = exclusive prefix of deg (fused scanA+scanC) ---- grid nb, 256
__global__ void scan_k(const int* __restrict__ deg, int* __restrict__ rowptr, int N) {
  __shared__ int red[256];
  __shared__ int sh[256];
  int t = threadIdx.x;
  int start = blockIdx.x * 256;
  // block prefix = sum deg[0..start) (redundant per block; L2-resident)
  int acc = 0;
  for (int idx = t; idx < start; idx += 256) acc += deg[idx];
  red[t] = acc;
  __syncthreads();
  for (int off = 128; off > 0; off >>= 1) {
    if (t < off) red[t] += red[t + off];
    __syncthreads();
  }
  int bpref = red[0];
  int i = start + t;
  int d = (i < N) ? deg[i] : 0;
  sh[t] = d;
  __syncthreads();
  for (int off = 1; off < 256; off <<= 1) {
    int u = (t >= off) ? sh[t - off] : 0;
    __syncthreads();
    sh[t] += u;
    __syncthreads();
  }
  int excl = sh[t] - d + bpref;
  if (i < N) {
    rowptr[i] = excl;
    if (i == N - 1) rowptr[N] = excl + d;
  }
}

// ---- scatter (no atomics): se16[rowptr[d]+ord[e]] = {src, ea01, ea23, 0} ----
__global__ void scatter_k(const int* __restrict__ ei, const float* __restrict__ ea,
                          const int* __restrict__ ord, const int* __restrict__ rowptr,
                          int4* __restrict__ se16, int E) {
  int e = blockIdx.x * 256 + threadIdx.x;
  if (e >= E) return;
  int s = ei[e], d = ei[E + e];
  float4 w = *(const float4*)(ea + (size_t)e * 4);
  int slot = rowptr[d] + ord[e];
  int4 ent;
  ent.x = s;
  ent.y = (int)((u32)f2bf(w.x) | ((u32)f2bf(w.y) << 16));
  ent.z = (int)((u32)f2bf(w.z) | ((u32)f2bf(w.w) << 16));
  ent.w = 0;
  se16[slot] = ent;
}

// ---- CONV1: gather1 + U1(LDS) + gemm1 MFMA + h1bf + bn1 stats + h1/x RAW POOLING ----
// grid ceil(N/16), block 256 (4 waves)
__global__ void __launch_bounds__(256) conv1_k(
    const int4* __restrict__ se16, const int* __restrict__ rowptr,
    const u16* __restrict__ xbf, const u16* __restrict__ Bp,
    const float* __restrict__ bm1, const float* __restrict__ be1,
    const float* __restrict__ bs1, u16* __restrict__ acc1c, u16* __restrict__ h1bf,
    float* __restrict__ bns1p, const int* __restrict__ batch,
    float* __restrict__ psumg, u32* __restrict__ pmaxg, u32* __restrict__ pming, int N) {
  __shared__ __align__(16) u16 Uls[16][72];
  __shared__ float degls[16];
  int tid = threadIdx.x;
  int nl = tid >> 4, q = tid & 15;
  int n = blockIdx.x * 16 + nl;
  bool nval = n < N;
  int j0 = nval ? rowptr[n] : 0;
  int j1 = nval ? rowptr[n + 1] : 0;
  int base = blockIdx.x * 16;
  int gid_lo = batch[base];
  int gid_hi = batch[min(base + 15, N - 1)];
  bool uni = (gid_lo == gid_hi);
  float v[20];
#pragma unroll
  for (int i = 0; i < 20; ++i) v[i] = 0.f;
  {
    int j = j0 + q;
    bool a0 = j < j1, a1 = (j + 16) < j1;
    int jj0 = a0 ? j : 0;
    int jj1 = a1 ? (j + 16) : 0;
    int4 p0 = se16[jj0];
    int4 p1 = se16[jj1];
    const uint4* xs0 = (const uint4*)(xbf + (size_t)(a0 ? p0.x : 0) * 16);
    uint4 x00 = xs0[0], x01 = xs0[1];
    const uint4* xs1 = (const uint4*)(xbf + (size_t)(a1 ? p1.x : 0) * 16);
    uint4 x10 = xs1[0], x11 = xs1[1];
    if (a0) {
      addp(v + 0, x00.x); addp(v + 2, x00.y); addp(v + 4, x00.z); addp(v + 6, x00.w);
      addp(v + 8, x01.x); addp(v + 10, x01.y); addp(v + 12, x01.z); addp(v + 14, x01.w);
      addp(v + 16, (u32)p0.y); addp(v + 18, (u32)p0.z);
    }
    if (a1) {
      addp(v + 0, x10.x); addp(v + 2, x10.y); addp(v + 4, x10.z); addp(v + 6, x10.w);
      addp(v + 8, x11.x); addp(v + 10, x11.y); addp(v + 12, x11.z); addp(v + 14, x11.w);
      addp(v + 16, (u32)p1.y); addp(v + 18, (u32)p1.z);
    }
    for (j += 32; j < j1; j += 16) {  // rare tail (deg > 32)
      int4 p = se16[j];
      const uint4* xs = (const uint4*)(xbf + (size_t)p.x * 16);
      uint4 x0 = xs[0], x1 = xs[1];
      addp(v + 0, x0.x); addp(v + 2, x0.y); addp(v + 4, x0.z); addp(v + 6, x0.w);
      addp(v + 8, x1.x); addp(v + 10, x1.y); addp(v + 12, x1.z); addp(v + 14, x1.w);
      addp(v + 16, (u32)p.y); addp(v + 18, (u32)p.z);
    }
  }
#pragma unroll
  for (int i = 0; i < 20; ++i) {
    v[i] += __shfl_xor(v[i], 1);
    v[i] += __shfl_xor(v[i], 2);
    v[i] += __shfl_xor(v[i], 4);
    v[i] += __shfl_xor(v[i], 8);
  }
  float degf = (float)(j1 - j0);
  const u16* xr = xbf + (size_t)n * 16;
  {  // U1 row -> LDS: [sums20, x(n)16, 0..]; lane q writes elems q*4..q*4+3
    u32 w2[2];
#pragma unroll
    for (int jj = 0; jj < 2; ++jj) {
      int t0 = q * 4 + 2 * jj, t1 = t0 + 1;
      u16 b0 = (t0 < 20) ? f2bf(v[t0]) : ((t0 < 36 && nval) ? xr[t0 - 20] : (u16)0);
      u16 b1 = (t1 < 20) ? f2bf(v[t1]) : ((t1 < 36 && nval) ? xr[t1 - 20] : (u16)0);
      w2[jj] = (u32)b0 | ((u32)b1 << 16);
    }
    *(uint2*)&Uls[nl][q * 4] = make_uint2(w2[0], w2[1]);
  }
  if (nval) {  // acc1c row: [sx16, sea4, deg, 0..]; lane q -> elems 2q,2q+1
    int t0 = q * 2, t1 = t0 + 1;
    float f0 = (t0 < 20) ? v[t0] : ((t0 == 20) ? degf : 0.f);
    float f1 = (t1 < 20) ? v[t1] : ((t1 == 20) ? degf : 0.f);
    *(u32*)(acc1c + (size_t)n * 32 + q * 2) = (u32)f2bf(f0) | ((u32)f2bf(f1) << 16);
  }
  if (q == 0) degls[nl] = degf;
  __syncthreads();
  // Phase B: 12 n-tile jobs over 4 waves; h1 raw pooling fused (f = 208+col)
  int w = tid >> 6, lane = tid & 63, rc = lane & 15, qd = lane >> 4;
  int slice = (blockIdx.x & 63) * 384;
  for (int nt = w; nt < 12; nt += 4) {
    f32x4 acc = {0.f, 0.f, 0.f, 0.f};
#pragma unroll
    for (int kb = 0; kb < 2; ++kb) {
      short8 av = *(const short8*)&Uls[rc][kb * 32 + qd * 8];
      short8 bv = *(const short8*)(Bp + (size_t)((kb * 4 + qd) * 192 + nt * 16 + rc) * 8);
      acc = __builtin_amdgcn_mfma_f32_16x16x32_bf16(av, bv, acc, 0, 0, 0);
    }
    int col = nt * 16 + rc;
    float bb = bm1[col] + be1[col], bsv = bs1[col];
    float ps = 0.f, pq = 0.f;
    float sl = 0.f, mxl = -3.4e38f, mnl = 3.4e38f;
    float vv[4];
#pragma unroll
    for (int r = 0; r < 4; ++r) {
      int ml = qd * 4 + r;
      int m = blockIdx.x * 16 + ml;
      float val = acc[r] + degls[ml] * bb + bsv;
      u16 vb = f2bf(val);
      float vr = bf2f(vb);  // pooled value = bf16-rounded (matches h1bf read)
      vv[r] = vr;
      if (m < N) {
        h1bf[(size_t)m * 192 + col] = vb;
        ps += val;
        pq += val * val;
        sl += vr;
        mxl = fmaxf(mxl, vr);
        mnl = fminf(mnl, vr);
      }
    }
    ps += __shfl_xor(ps, 16); ps += __shfl_xor(ps, 32);
    pq += __shfl_xor(pq, 16); pq += __shfl_xor(pq, 32);
    if (uni) {
      sl += __shfl_xor(sl, 16); sl += __shfl_xor(sl, 32);
      mxl = fmaxf(mxl, __shfl_xor(mxl, 16)); mxl = fmaxf(mxl, __shfl_xor(mxl, 32));
      mnl = fminf(mnl, __shfl_xor(mnl, 16)); mnl = fminf(mnl, __shfl_xor(mnl, 32));
    }
    if (qd == 0) {
      atomAddF(&bns1p[slice + col], ps);
      atomAddF(&bns1p[slice + 192 + col], pq);
      if (uni) {
        int pidx = gid_lo * 416 + 208 + col;
        atomAddF(&psumg[pidx], sl);
        atomicMax(&pmaxg[pidx], encf(mxl));
        atomicMin(&pming[pidx], encf(mnl));
      }
    }
    if (!uni) {  // boundary block: per-run atomics over this lane's 4 rows
      int cg = -1;
      float rs = 0.f, rmx = -3.4e38f, rmn = 3.4e38f;
#pragma unroll
      for (int r = 0; r < 4; ++r) {
        int m = blockIdx.x * 16 + qd * 4 + r;
        if (m >= N) continue;
        int g = batch[m];
        if (g != cg) {
          if (cg >= 0) {
            int pidx = cg * 416 + 208 + col;
            atomAddF(&psumg[pidx], rs);
            atomicMax(&pmaxg[pidx], encf(rmx));
            atomicMin(&pming[pidx], encf(rmn));
          }
          cg = g; rs = 0.f; rmx = -3.4e38f; rmn = 3.4e38f;
        }
        rs += vv[r];
        rmx = fmaxf(rmx, vv[r]);
        rmn = fminf(rmn, vv[r]);
      }
      if (cg >= 0) {
        int pidx = cg * 416 + 208 + col;
        atomAddF(&psumg[pidx], rs);
        atomicMax(&pmaxg[pidx], encf(rmx));
        atomicMin(&pming[pidx], encf(rmn));
      }
    }
  }
  // ---- pool x from Uls cols 20..35 (raw): -> global feature 400+c, c in [0,16) ----
  if (tid < 16) {
    int c = tid;
    int rows = min(16, N - base);
    if (uni) {
      float s = 0.f, mx = -3.4e38f, mn = 3.4e38f;
      for (int ml = 0; ml < rows; ++ml) {
        float vx = bf2f(Uls[ml][20 + c]);
        s += vx;
        mx = fmaxf(mx, vx);
        mn = fminf(mn, vx);
      }
      int pidx = gid_lo * 416 + 400 + c;
      atomAddF(&psumg[pidx], s);
      atomicMax(&pmaxg[pidx], encf(mx));
      atomicMin(&pming[pidx], encf(mn));
    } else {
      int cg = -1;
      float rs = 0.f, rmx = -3.4e38f, rmn = 3.4e38f;
      for (int ml = 0; ml < rows; ++ml) {
        int g = batch[base + ml];
        if (g != cg) {
          if (cg >= 0) {
            int pidx = cg * 416 + 400 + c;
            atomAddF(&psumg[pidx], rs);
            atomicMax(&pmaxg[pidx], encf(rmx));
            atomicMin(&pming[pidx], encf(rmn));
          }
          cg = g; rs = 0.f; rmx = -3.4e38f; rmn = 3.4e38f;
        }
        float vx = bf2f(Uls[ml][20 + c]);
        rs += vx;
        rmx = fmaxf(rmx, vx);
        rmn = fminf(rmn, vx);
      }
      if (cg >= 0) {
        int pidx = cg * 416 + 400 + c;
        atomAddF(&psumg[pidx], rs);
        atomicMax(&pmaxg[pidx], encf(rmx));
        atomicMin(&pming[pidx], encf(rmn));
      }
    }
  }
}

// ---- bn1 finalize ---- 1 block, 256 threads
__global__ void bnfin1_k(const float* __restrict__ bns1p, const float* __restrict__ g1,
                         const float* __restrict__ bta1, float Ninv,
                         float* __restrict__ aff1) {
  int c = threadIdx.x;
  if (c >= 192) return;
  float sm = 0.f, sq = 0.f;
  for (int k = 0; k < 64; ++k) {
    sm += bns1p[k * 384 + c];
    sq += bns1p[k * 384 + 192 + c];
  }
  float m1 = sm * Ninv;
  float var = sq * Ninv - m1 * m1;
  float s1 = g1[c] * rsqrtf(var + 1e-5f);
  aff1[c] = s1;
  aff1[192 + c] = bta1[c] - m1 * s1;
}

// ---- CONV2: gather2 + U2 + X1 staged + gemms + bn2 stats + h2 RAW POOLING only ----
// grid ceil(N/16), block 256 (4 waves). h2 never materialized.
__global__ void __launch_bounds__(256) conv2_k(
    const int4* __restrict__ se16, const int* __restrict__ rowptr,
    const u16* __restrict__ acc1c, const u16* __restrict__ h1bf,
    const u16* __restrict__ xbf, const u16* __restrict__ Bp1, const u16* __restrict__ Bp2,
    const float* __restrict__ bm1, const float* __restrict__ be1,
    const float* __restrict__ bs1, const float* __restrict__ aff1,
    const float* __restrict__ We2, const float* __restrict__ bm2,
    const float* __restrict__ be2, float* __restrict__ bns2p,
    const int* __restrict__ batch, float* __restrict__ psumg,
    u32* __restrict__ pmaxg, u32* __restrict__ pming, int N) {
  __shared__ __align__(16) u16 Uls[16][72];
  __shared__ __align__(16) u16 Vls[16][232];
  __shared__ __align__(16) u16 X1ls[16][208];  // cols 0..191 h1 raw, 192..207 x raw
  __shared__ float degls[16], sdegls[16], eals[16][4];
  int tid = threadIdx.x;
  int nl = tid >> 4, q = tid & 15;
  int n = blockIdx.x * 16 + nl;
  bool nval = n < N;
  int j0 = nval ? rowptr[n] : 0;
  int j1 = nval ? rowptr[n + 1] : 0;
  int base = blockIdx.x * 16;
  int gid_lo = batch[base];
  int gid_hi = batch[min(base + 15, N - 1)];
  bool uni = (gid_lo == gid_hi);

  // ---- stage X1 rows: issue coalesced loads first (overlap with gather) ----
  uint4 sg0, sg1, sgx;
  int r0 = tid / 24, c0 = tid % 24;                 // rows 0..10
  int r1 = (tid + 256) / 24, c1 = (tid + 256) % 24; // rows 10..15 (tid<128)
  {
    int gr = base + r0;
    sg0 = (gr < N) ? *(const uint4*)(h1bf + (size_t)gr * 192 + c0 * 8)
                   : make_uint4(0, 0, 0, 0);
  }
  if (tid < 128) {
    int gr = base + r1;
    sg1 = (gr < N) ? *(const uint4*)(h1bf + (size_t)gr * 192 + c1 * 8)
                   : make_uint4(0, 0, 0, 0);
  }
  if (tid < 32) {
    int gr = base + (tid >> 1);
    sgx = (gr < N) ? *(const uint4*)(xbf + (size_t)gr * 16 + (tid & 1) * 8)
                   : make_uint4(0, 0, 0, 0);
  }

  float v[21];
#pragma unroll
  for (int i = 0; i < 21; ++i) v[i] = 0.f;
  {
    // Unrolled 2-deep gather prefetch (see conv1_k).
    int j = j0 + q;
    bool a0 = j < j1, a1 = (j + 16) < j1;
    int jj0 = a0 ? j : 0;
    int jj1 = a1 ? (j + 16) : 0;
    int4 p0 = se16[jj0];
    int4 p1 = se16[jj1];
    const uint4* cr0 = (const uint4*)(acc1c + (size_t)(a0 ? p0.x : 0) * 32);
    uint4 c00 = cr0[0], c01 = cr0[1], c02 = cr0[2];
    const uint4* cr1 = (const uint4*)(acc1c + (size_t)(a1 ? p1.x : 0) * 32);
    uint4 c10 = cr1[0], c11 = cr1[1], c12 = cr1[2];
    if (a0) {
      addp(v + 0, c00.x); addp(v + 2, c00.y); addp(v + 4, c00.z); addp(v + 6, c00.w);
      addp(v + 8, c01.x); addp(v + 10, c01.y); addp(v + 12, c01.z); addp(v + 14, c01.w);
      addp(v + 16, c02.x); addp(v + 18, c02.y);
      v[20] += bf2f((u16)c02.z);
    }
    if (a1) {
      addp(v + 0, c10.x); addp(v + 2, c10.y); addp(v + 4, c10.z); addp(v + 6, c10.w);
      addp(v + 8, c11.x); addp(v + 10, c11.y); addp(v + 12, c11.z); addp(v + 14, c11.w);
      addp(v + 16, c12.x); addp(v + 18, c12.y);
      v[20] += bf2f((u16)c12.z);
    }
    for (j += 32; j < j1; j += 16) {  // rare tail (deg > 32)
      int s = se16[j].x;
      const uint4* cr = (const uint4*)(acc1c + (size_t)s * 32);
      uint4 c0 = cr[0], c1 = cr[1], c2 = cr[2];
      addp(v + 0, c0.x); addp(v + 2, c0.y); addp(v + 4, c0.z); addp(v + 6, c0.w);
      addp(v + 8, c1.x); addp(v + 10, c1.y); addp(v + 12, c1.z); addp(v + 14, c1.w);
      addp(v + 16, c2.x); addp(v + 18, c2.y);
      v[20] += bf2f((u16)c2.z);
    }
  }

  // ---- write staged X1 rows to LDS (loads had gather-time to land) ----
  *(uint4*)&X1ls[r0][c0 * 8] = sg0;
  if (tid < 128) *(uint4*)&X1ls[r1][c1 * 8] = sg1;
  if (tid < 32) *(uint4*)&X1ls[tid >> 1][192 + (tid & 1) * 8] = sgx;

#pragma unroll
  for (int i = 0; i < 21; ++i) {
    v[i] += __shfl_xor(v[i], 1);
    v[i] += __shfl_xor(v[i], 2);
    v[i] += __shfl_xor(v[i], 4);
    v[i] += __shfl_xor(v[i], 8);
  }
  const u16* selfr = acc1c + (size_t)n * 32;
  {  // U2 row -> LDS: [sums20, self sx16, 0..]; lane q writes elems q*4..q*4+3
    u32 w2[2];
#pragma unroll
    for (int jj = 0; jj < 2; ++jj) {
      int t0 = q * 4 + 2 * jj, t1 = t0 + 1;
      u16 b0 = (t0 < 20) ? f2bf(v[t0]) : ((t0 < 36 && nval) ? selfr[t0 - 20] : (u16)0);
      u16 b1 = (t1 < 20) ? f2bf(v[t1]) : ((t1 < 36 && nval) ? selfr[t1 - 20] : (u16)0);
      w2[jj] = (u32)b0 | ((u32)b1 << 16);
    }
    *(uint2*)&Uls[nl][q * 4] = make_uint2(w2[0], w2[1]);
  }
  {  // V tail cols [192..224): self sx16 then zeros; lane q -> elems 192+2q, +1
    int t0 = q * 2, t1 = t0 + 1;
    u16 b0 = (t0 < 16 && nval) ? selfr[t0] : (u16)0;
    u16 b1 = (t1 < 16 && nval) ? selfr[t1] : (u16)0;
    *(u32*)&Vls[nl][192 + q * 2] = (u32)b0 | ((u32)b1 << 16);
  }
  if (q == 0) sdegls[nl] = v[20];
  if (q == 1) degls[nl] = nval ? bf2f(selfr[20]) : 0.f;
  if (q == 2) {
#pragma unroll
    for (int k = 0; k < 4; ++k) eals[nl][k] = nval ? bf2f(selfr[16 + k]) : 0.f;
  }
  __syncthreads();
  // Phase B: gemmq2 -> Vls[:,0..192), 12 jobs / 4 waves
  int w = tid >> 6, lane = tid & 63, rc = lane & 15, qd = lane >> 4;
  for (int nt = w; nt < 12; nt += 4) {
    f32x4 acc = {0.f, 0.f, 0.f, 0.f};
#pragma unroll
    for (int kb = 0; kb < 2; ++kb) {
      short8 av = *(const short8*)&Uls[rc][kb * 32 + qd * 8];
      short8 bv = *(const short8*)(Bp1 + (size_t)((kb * 4 + qd) * 192 + nt * 16 + rc) * 8);
      acc = __builtin_amdgcn_mfma_f32_16x16x32_bf16(av, bv, acc, 0, 0, 0);
    }
    int col = nt * 16 + rc;
    float s1 = aff1[col], t1 = aff1[192 + col];
    float bb = bm1[col] + be1[col], bsv = bs1[col];
#pragma unroll
    for (int r = 0; r < 4; ++r) {
      int ml = qd * 4 + r;
      float qv = acc[r] + sdegls[ml] * bb + degls[ml] * bsv;
      Vls[ml][col] = f2bf(qv * s1 + degls[ml] * t1);
    }
  }
  __syncthreads();
  // Phase C: gemm2 + bn2 stats + h2 pooling (raw); NO h2 store at all.
  int slice = (blockIdx.x & 63) * 832;
  for (int nt = w; nt < 13; nt += 4) {
    f32x4 acc = {0.f, 0.f, 0.f, 0.f};
#pragma unroll
    for (int kb = 0; kb < 7; ++kb) {
      short8 av = *(const short8*)&Vls[rc][kb * 32 + qd * 8];
      short8 bv = *(const short8*)(Bp2 + (size_t)((kb * 4 + qd) * 208 + nt * 16 + rc) * 8);
      acc = __builtin_amdgcn_mfma_f32_16x16x32_bf16(av, bv, acc, 0, 0, 0);
    }
    int col = nt * 16 + rc;
    float w0 = We2[col], w1 = We2[208 + col], w2 = We2[416 + col], w3 = We2[624 + col];
    float bb2 = bm2[col] + be2[col];
    bool c192 = col < 192;
    float s1 = c192 ? aff1[col] : 0.f;
    float t1 = c192 ? aff1[192 + col] : 0.f;
    float ps = 0.f, pq = 0.f;
    float sl = 0.f, mxl = -3.4e38f, mnl = 3.4e38f;
    float vv[4];
#pragma unroll
    for (int r = 0; r < 4; ++r) {
      int ml = qd * 4 + r;
      int m = blockIdx.x * 16 + ml;
      bool mv = m < N;
      float x1 = bf2f(X1ls[ml][col]);
      if (c192) x1 = x1 * s1 + t1;
      float val = acc[r] + eals[ml][0] * w0 + eals[ml][1] * w1 + eals[ml][2] * w2 +
                  eals[ml][3] * w3 + degls[ml] * bb2 + x1;
      vv[r] = val;
      if (mv) {
        ps += val;
        pq += val * val;
        sl += val;
        mxl = fmaxf(mxl, val);
        mnl = fminf(mnl, val);
      }
    }
    ps += __shfl_xor(ps, 16); ps += __shfl_xor(ps, 32);
    pq += __shfl_xor(pq, 16); pq += __shfl_xor(pq, 32);
    if (uni) {
      sl += __shfl_xor(sl, 16); sl += __shfl_xor(sl, 32);
      mxl = fmaxf(mxl, __shfl_xor(mxl, 16)); mxl = fmaxf(mxl, __shfl_xor(mxl, 32));
      mnl = fminf(mnl, __shfl_xor(mnl, 16)); mnl = fminf(mnl, __shfl_xor(mnl, 32));
    }
    if (qd == 0) {
      atomAddF(&bns2p[slice + col], ps);
      atomAddF(&bns2p[slice + 416 + col], pq);
      if (uni) {
        int pidx = gid_lo * 416 + col;
        atomAddF(&psumg[pidx], sl);
        atomicMax(&pmaxg[pidx], encf(mxl));
        atomicMin(&pming[pidx], encf(mnl));
      }
    }
    if (!uni) {  // boundary block (~4%): per-run atomics over this lane's 4 rows
      int cg = -1;
      float rs = 0.f, rmx = -3.4e38f, rmn = 3.4e38f;
#pragma unroll
      for (int r = 0; r < 4; ++r) {
        int m = blockIdx.x * 16 + qd * 4 + r;
        if (m >= N) continue;
        int g = batch[m];
        if (g != cg) {
          if (cg >= 0) {
            int pidx = cg * 416 + col;
            atomAddF(&psumg[pidx], rs);
            atomicMax(&pmaxg[pidx], encf(rmx));
            atomicMin(&pming[pidx], encf(rmn));
          }
          cg = g; rs = 0.f; rmx = -3.4e38f; rmn = 3.4e38f;
        }
        rs += vv[r];
        rmx = fmaxf(rmx, vv[r]);
        rmn = fminf(rmn, vv[r]);
      }
      if (cg >= 0) {
        int pidx = cg * 416 + col;
        atomAddF(&psumg[pidx], rs);
        atomicMax(&pmaxg[pidx], encf(rmx));
        atomicMin(&pming[pidx], encf(rmn));
      }
    }
  }
}

// ---- MLP layer 1: pooled A built in LDS (pooledprep folded) + MFMA, K/4 waves ----
// grid=(4,39), block 256
__global__ void __launch_bounds__(256) mlpgemm_k(
    const float* __restrict__ psumg, const u32* __restrict__ pmaxg,
    const u32* __restrict__ pming, const int* __restrict__ gstart,
    const int* __restrict__ gend, const float* __restrict__ bns2p,
    const float* __restrict__ aff1, const float* __restrict__ g2,
    const float* __restrict__ bta2, float Ninv, const u16* __restrict__ Bp,
    const float* __restrict__ b1, const float* __restrict__ al,
    float* __restrict__ hid) {
  __shared__ float scs[416], shs[416];
  __shared__ __align__(16) u16 Als[16][1256];  // stride-padded (1256) vs 1248
  __shared__ __align__(16) float part[3][64][4];
  int tid = threadIdx.x;
  int mt = blockIdx.x, nt = blockIdx.y;
  // phase 0: bn affines (bns2p L2-resident; 156 blocks redundant = cheap)
  for (int f = tid; f < 416; f += 256) {
    float sc, sh;
    if (f < 208) {
      float sm = 0.f, sq = 0.f;
      for (int k = 0; k < 64; ++k) {
        sm += bns2p[k * 832 + f];
        sq += bns2p[k * 832 + 416 + f];
      }
      float m2 = sm * Ninv;
      float var = sq * Ninv - m2 * m2;
      sc = g2[f] * rsqrtf(var + 1e-5f);
      sh = bta2[f] - m2 * sc;
    } else if (f < 400) {
      sc = aff1[f - 208];
      sh = aff1[192 + (f - 208)];
    } else {
      sc = 1.f;
      sh = 0.f;
    }
    scs[f] = sc;
    shs[f] = sh;
  }
  __syncthreads();
  // phase 1: build 16 A-rows (graphs mt*16..mt*16+15) in LDS
  for (int e = tid; e < 16 * 416; e += 256) {
    int g = e / 416, f = e % 416;
    int b = mt * 16 + g;
    int cnt = gend[b] - gstart[b] + 1;
    float inv = 1.f / (float)max(cnt, 1);
    float s = psumg[b * 416 + f];
    float mx = decf(pmaxg[b * 416 + f]);
    float mn = decf(pming[b * 416 + f]);
    float sc = scs[f], sh = shs[f];
    float sumf = sc * s + (float)cnt * sh;
    float mxf = (sc >= 0.f) ? sc * mx + sh : sc * mn + sh;
    Als[g][f] = f2bf(sumf);
    Als[g][416 + f] = f2bf((cnt > 0) ? mxf : 0.f);
    Als[g][832 + f] = f2bf(sumf * inv);
  }
  __syncthreads();
  // phase 2: MFMA, K split over 4 waves + LDS reduce
  int w = tid >> 6, lane = tid & 63;
  int rc = lane & 15, qd = lane >> 4;
  f32x4 acc = {0.f, 0.f, 0.f, 0.f};
  const u16* Bq = Bp + (size_t)(qd * 624 + nt * 16 + rc) * 8;
  for (int kb = w; kb < 39; kb += 4) {
    short8 av = *(const short8*)&Als[rc][kb * 32 + qd * 8];
    short8 bv = *(const short8*)(Bq + (size_t)kb * 4 * 624 * 8);
    acc = __builtin_amdgcn_mfma_f32_16x16x32_bf16(av, bv, acc, 0, 0, 0);
  }
  if (w > 0) *(f32x4*)&part[w - 1][lane][0] = acc;
  __syncthreads();
  if (w == 0) {
#pragma unroll
    for (int j = 0; j < 3; ++j) {
      f32x4 p = *(const f32x4*)&part[j][lane][0];
      acc[0] += p[0]; acc[1] += p[1]; acc[2] += p[2]; acc[3] += p[3];
    }
    int col = nt * 16 + rc;
    float bb = b1[col], alpha = al[0];
    int m0 = mt * 16 + qd * 4;
#pragma unroll
    for (int r = 0; r < 4; ++r) {
      float v = acc[r] + bb;
      hid[(size_t)(m0 + r) * 624 + col] = (v >= 0.f) ? v : alpha * v;
    }
  }
}

// ---- logits + log_softmax ---- grid=64, block=64
__global__ void head_k(const float* __restrict__ hid, const float* __restrict__ W2,
                       const float* __restrict__ b2, float* __restrict__ out) {
  int b = blockIdx.x, t = threadIdx.x;
  float p0 = 0.f, p1 = 0.f;
  for (int k = t; k < 624; k += 64) {
    float h = hid[(size_t)b * 624 + k];
    p0 += h * W2[k * 2];
    p1 += h * W2[k * 2 + 1];
  }
#pragma unroll
  for (int off = 32; off > 0; off >>= 1) {
    p0 += __shfl_down(p0, off);
    p1 += __shfl_down(p1, off);
  }
  if (t == 0) {
    float l0 = p0 + b2[0], l1 = p1 + b2[1];
    float m = fmaxf(l0, l1);
    float lse = m + logf(expf(l0 - m) + expf(l1 - m));
    out[b * 2] = l0 - lse;
    out[b * 2 + 1] = l1 - lse;
  }
}

extern "C" void kernel_launch(void* const* d_in, const int* in_sizes, int n_in,
                              void* d_out, int out_size, void* d_ws, size_t ws_size,
                              hipStream_t stream) {
  const float* x = (const float*)d_in[0];
  const int* ei = (const int*)d_in[1];
  const float* ea = (const float*)d_in[2];
  const int* batch = (const int*)d_in[3];
  const float* Wm1 = (const float*)d_in[4];
  const float* bm1 = (const float*)d_in[5];
  const float* We1 = (const float*)d_in[6];
  const float* be1 = (const float*)d_in[7];
  const float* Ws1 = (const float*)d_in[8];
  const float* bs1 = (const float*)d_in[9];
  const float* g1 = (const float*)d_in[10];
  const float* bta1 = (const float*)d_in[11];
  const float* Wm2 = (const float*)d_in[12];
  const float* bm2 = (const float*)d_in[13];
  const float* We2 = (const float*)d_in[14];
  const float* be2 = (const float*)d_in[15];
  const float* g2 = (const float*)d_in[16];
  const float* bta2 = (const float*)d_in[17];
  const float* Wl1 = (const float*)d_in[18];
  const float* bl1 = (const float*)d_in[19];
  const float* alpha = (const float*)d_in[20];
  const float* Wl2 = (const float*)d_in[21];
  const float* bl2 = (const float*)d_in[22];
  float* out = (float*)d_out;

  const int N = in_sizes[3];      // 50000
  const int E = in_sizes[2] / 4;  // 800000
  const int nb = (N + 255) / 256; // 196 (<=256)
  const float Ninv = 1.f / (float)N;

  float* ws = (float*)d_ws;
  size_t o = 0;
  u16* acc1c = (u16*)(ws + o); o += (size_t)N * 16;  // N*32 u16
  u16* h1bf = (u16*)(ws + o);  o += (size_t)N * 96;  // N*192 u16
  u16* xbf = (u16*)(ws + o);   o += (size_t)N * 8;   // N*16 u16
  u16* Wp1 = (u16*)(ws + o);   o += 6144;
  u16* Wp2 = (u16*)(ws + o);   o += 23296;
  u16* Wp3 = (u16*)(ws + o);   o += 389376;
  float* hid = ws + o;    o += 64 * 624;
  float* bns1p = ws + o;  o += 64 * 384;
  float* bns2p = ws + o;  o += 64 * 832;
  float* aff1 = ws + o;   o += 384;
  float* psumg = ws + o;  o += 64 * 416;
  u32* pmaxg = (u32*)(ws + o); o += 64 * 416;
  u32* pming = (u32*)(ws + o); o += 64 * 416;
  int* gstart = (int*)(ws + o); o += 64;
  int* gend = (int*)(ws + o);   o += 64;
  int* deg = (int*)(ws + o);    o += N;
  int* rowptr = (int*)(ws + o); o += N + 1;
  int* ord = (int*)(ws + o);    o += E;
  o = (o + 3) & ~(size_t)3;  // 16B align for int4
  int4* se16 = (int4*)(ws + o); o += (size_t)4 * E;

  const int gconv = (N + 15) / 16;  // 3125
  prep_k<<<(E + 255) / 256, 256, 0, stream>>>(Wm1, We1, Ws1, Wm2, Wl1, x, batch, Wp1, Wp2,
                                              Wp3, xbf, gstart, gend, deg, bns1p, bns2p,
                                              psumg, pmaxg, pming, N, E);
  count_k<<<(E + 255) / 256, 256, 0, stream>>>(ei, deg, ord, E);
  scan_k<<<nb, 256, 0, stream>>>(deg, rowptr, N);
  scatter_k<<<(E + 255) / 256, 256, 0, stream>>>(ei, ea, ord, rowptr, se16, E);
  conv1_k<<<gconv, 256, 0, stream>>>(se16, rowptr, xbf, Wp1, bm1, be1, bs1, acc1c, h1bf,
                                     bns1p, batch, psumg, pmaxg, pming, N);
  bnfin1_k<<<1, 256, 0, stream>>>(bns1p, g1, bta1, Ninv, aff1);
  conv2_k<<<gconv, 256, 0, stream>>>(se16, rowptr, acc1c, h1bf, xbf, Wp1, Wp2, bm1, be1,
                                     bs1, aff1, We2, bm2, be2, bns2p, batch, psumg,
                                     pmaxg, pming, N);
  mlpgemm_k<<<dim3(4, 39), 256, 0, stream>>>(psumg, pmaxg, pming, gstart, gend, bns2p,
                                             aff1, g2, bta2, Ninv, Wp3, bl1, alpha, hid);
  head_k<<<64, 64, 0, stream>>>(hid, Wl2, bl2, out);
}

// Round 18
// 276.844 us; speedup vs baseline: 1.1509x; 1.1234x over previous
//
#include <hip/hip_runtime.h>

typedef __attribute__((ext_vector_type(8))) short short8;
typedef __attribute__((ext_vector_type(4))) float f32x4;
typedef unsigned short u16;
typedef unsigned int u32;

__device__ __forceinline__ u16 f2bf(float f) {
  u32 u = __float_as_uint(f);
  u = (u + 0x7fffu + ((u >> 16) & 1u)) >> 16;
  return (u16)u;
}
__device__ __forceinline__ float bf2f(u16 v) { return __uint_as_float((u32)v << 16); }
__device__ __forceinline__ void atomAddF(float* p, float v) { unsafeAtomicAdd(p, v); }
__device__ __forceinline__ void addp(float* v, u32 p) {
  v[0] += bf2f((u16)p);
  v[1] += bf2f((u16)(p >> 16));
}
// order-preserving float<->u32 encode for atomicMax/atomicMin
__device__ __forceinline__ u32 encf(float f) {
  u32 u = __float_as_uint(f);
  return (u & 0x80000000u) ? ~u : (u | 0x80000000u);
}
__device__ __forceinline__ float decf(u32 u) {
  return (u & 0x80000000u) ? __uint_as_float(u ^ 0x80000000u) : __uint_as_float(~u);
}

// ---- prep: pack bf16 weights + x->bf16 + graph bounds + zero scratch ---- grid E/256
__global__ void prep_k(const float* __restrict__ Wm1, const float* __restrict__ We1,
                       const float* __restrict__ Ws1, const float* __restrict__ Wm2,
                       const float* __restrict__ Wl1, const float* __restrict__ x,
                       const int* __restrict__ batch, u16* __restrict__ Wp1,
                       u16* __restrict__ Wp2, u16* __restrict__ Wp3,
                       u16* __restrict__ xbf, int* __restrict__ gstart,
                       int* __restrict__ gend, int* __restrict__ deg,
                       float* __restrict__ bns1p, float* __restrict__ bns2p,
                       float* __restrict__ psumg, u32* __restrict__ pmaxg,
                       u32* __restrict__ pming, int N, int E) {
  int tid = blockIdx.x * 256 + threadIdx.x;
  if (tid < 64 * 192) {  // Wcat1 = [Wm1(16); We1(4); Ws1(16)], pad K to 64
    int k = tid / 192, n = tid % 192;
    float v = 0.f;
    if (k < 16) v = Wm1[k * 192 + n];
    else if (k < 20) v = We1[(k - 16) * 192 + n];
    else if (k < 36) v = Ws1[(k - 20) * 192 + n];
    Wp1[((k >> 3) * 192 + n) * 8 + (k & 7)] = f2bf(v);
  }
  if (tid < 224 * 208) {  // W_msg2, pad K 208->224
    int k = tid / 208, n = tid % 208;
    float v = (k < 208) ? Wm2[k * 208 + n] : 0.f;
    Wp2[((k >> 3) * 208 + n) * 8 + (k & 7)] = f2bf(v);
  }
  if (tid < N * 8) {  // x -> bf16, 2 elems/thread
    float2 p = *(const float2*)(x + (size_t)tid * 2);
    *(u32*)(xbf + (size_t)tid * 2) = (u32)f2bf(p.x) | ((u32)f2bf(p.y) << 16);
  }
  if (tid < N) {
    int b = batch[tid];
    if (tid == 0 || batch[tid - 1] != b) gstart[b] = tid;
    if (tid == N - 1 || batch[tid + 1] != b) gend[b] = tid;
    deg[tid] = 0;
  }
  if (tid < 64 * 384) bns1p[tid] = 0.f;
  if (tid < 64 * 832) bns2p[tid] = 0.f;
  if (tid < 64 * 416) {  // pooled accumulators: sum=0, max=enc(-inf), min=enc(+inf)
    psumg[tid] = 0.f;
    pmaxg[tid] = 0x007FFFFFu;
    pming[tid] = 0xFF800000u;
  }
  if (tid < 1248 * 624) {
    int k = tid / 624, n = tid % 624;
    Wp3[((size_t)(k >> 3) * 624 + n) * 8 + (k & 7)] = f2bf(Wl1[(size_t)k * 624 + n]);
  }
}

// ---- count + within-row ordinal ----
__global__ void count_k(const int* __restrict__ ei, int* __restrict__ deg,
                        int* __restrict__ ord, int E) {
  int e = blockIdx.x * 256 + threadIdx.x;
  if (e >= E) return;
  ord[e] = atomicAdd(&deg[ei[E + e]], 1);
}

__global__ void scanA_k(const int* __restrict__ deg, int* __restrict__ bsum, int N) {
  __shared__ int sh[256];
  int t = threadIdx.x;
  int i = blockIdx.x * 256 + t;
  sh[t] = (i < N) ? deg[i] : 0;
  __syncthreads();
  for (int off = 128; off > 0; off >>= 1) {
    if (t < off) sh[t] += sh[t + off];
    __syncthreads();
  }
  if (t == 0) bsum[blockIdx.x] = sh[0];
}

__global__ void scanC_k(const int* __restrict__ deg, const int* __restrict__ bsum,
                        int* __restrict__ rowptr, int N, int nb) {
  __shared__ int sb2[256];
  __shared__ int sh[256];
  int t = threadIdx.x;
  int bv = (t < nb) ? bsum[t] : 0;
  sb2[t] = bv;
  __syncthreads();
  for (int off = 1; off < 256; off <<= 1) {
    int u = (t >= off) ? sb2[t - off] : 0;
    __syncthreads();
    sb2[t] += u;
    __syncthreads();
  }
  int bpref = (blockIdx.x == 0) ? 0 : sb2[blockIdx.x - 1];
  int i = blockIdx.x * 256 + t;
  int d = (i < N) ? deg[i] : 0;
  sh[t] = d;
  __syncthreads();
  for (int off = 1; off < 256; off <<= 1) {
    int u = (t >= off) ? sh[t - off] : 0;
    __syncthreads();
    sh[t] += u;
    __syncthreads();
  }
  int excl = sh[t] - d + bpref;
  if (i < N) {
    rowptr[i] = excl;
    if (i == N - 1) rowptr[N] = excl + d;
  }
}

// ---- scatter (no atomics): se16[rowptr[d]+ord[e]] = {src, ea01, ea23, 0} ----
__global__ void scatter_k(const int* __restrict__ ei, const float* __restrict__ ea,
                          const int* __restrict__ ord, const int* __restrict__ rowptr,
                          int4* __restrict__ se16, int E) {
  int e = blockIdx.x * 256 + threadIdx.x;
  if (e >= E) return;
  int s = ei[e], d = ei[E + e];
  float4 w = *(const float4*)(ea + (size_t)e * 4);
  int slot = rowptr[d] + ord[e];
  int4 ent;
  ent.x = s;
  ent.y = (int)((u32)f2bf(w.x) | ((u32)f2bf(w.y) << 16));
  ent.z = (int)((u32)f2bf(w.z) | ((u32)f2bf(w.w) << 16));
  ent.w = 0;
  se16[slot] = ent;
}

// ---- CONV1: gather1 + U1(LDS) + gemm1 MFMA + h1bf + bn1 stats + h1/x RAW POOLING ----
// grid ceil(N/16), block 256 (4 waves)
__global__ void __launch_bounds__(256) conv1_k(
    const int4* __restrict__ se16, const int* __restrict__ rowptr,
    const u16* __restrict__ xbf, const u16* __restrict__ Bp,
    const float* __restrict__ bm1, const float* __restrict__ be1,
    const float* __restrict__ bs1, u16* __restrict__ acc1c, u16* __restrict__ h1bf,
    float* __restrict__ bns1p, const int* __restrict__ batch,
    float* __restrict__ psumg, u32* __restrict__ pmaxg, u32* __restrict__ pming, int N) {
  __shared__ __align__(16) u16 Uls[16][72];
  __shared__ float degls[16];
  int tid = threadIdx.x;
  int nl = tid >> 4, q = tid & 15;
  int n = blockIdx.x * 16 + nl;
  bool nval = n < N;
  int j0 = nval ? rowptr[n] : 0;
  int j1 = nval ? rowptr[n + 1] : 0;
  int base = blockIdx.x * 16;
  int gid_lo = batch[base];
  int gid_hi = batch[min(base + 15, N - 1)];
  bool uni = (gid_lo == gid_hi);
  float v[20];
#pragma unroll
  for (int i = 0; i < 20; ++i) v[i] = 0.f;
  {
    int j = j0 + q;
    bool a0 = j < j1, a1 = (j + 16) < j1;
    int jj0 = a0 ? j : 0;
    int jj1 = a1 ? (j + 16) : 0;
    int4 p0 = se16[jj0];
    int4 p1 = se16[jj1];
    const uint4* xs0 = (const uint4*)(xbf + (size_t)(a0 ? p0.x : 0) * 16);
    uint4 x00 = xs0[0], x01 = xs0[1];
    const uint4* xs1 = (const uint4*)(xbf + (size_t)(a1 ? p1.x : 0) * 16);
    uint4 x10 = xs1[0], x11 = xs1[1];
    if (a0) {
      addp(v + 0, x00.x); addp(v + 2, x00.y); addp(v + 4, x00.z); addp(v + 6, x00.w);
      addp(v + 8, x01.x); addp(v + 10, x01.y); addp(v + 12, x01.z); addp(v + 14, x01.w);
      addp(v + 16, (u32)p0.y); addp(v + 18, (u32)p0.z);
    }
    if (a1) {
      addp(v + 0, x10.x); addp(v + 2, x10.y); addp(v + 4, x10.z); addp(v + 6, x10.w);
      addp(v + 8, x11.x); addp(v + 10, x11.y); addp(v + 12, x11.z); addp(v + 14, x11.w);
      addp(v + 16, (u32)p1.y); addp(v + 18, (u32)p1.z);
    }
    for (j += 32; j < j1; j += 16) {  // rare tail (deg > 32)
      int4 p = se16[j];
      const uint4* xs = (const uint4*)(xbf + (size_t)p.x * 16);
      uint4 x0 = xs[0], x1 = xs[1];
      addp(v + 0, x0.x); addp(v + 2, x0.y); addp(v + 4, x0.z); addp(v + 6, x0.w);
      addp(v + 8, x1.x); addp(v + 10, x1.y); addp(v + 12, x1.z); addp(v + 14, x1.w);
      addp(v + 16, (u32)p.y); addp(v + 18, (u32)p.z);
    }
  }
#pragma unroll
  for (int i = 0; i < 20; ++i) {
    v[i] += __shfl_xor(v[i], 1);
    v[i] += __shfl_xor(v[i], 2);
    v[i] += __shfl_xor(v[i], 4);
    v[i] += __shfl_xor(v[i], 8);
  }
  float degf = (float)(j1 - j0);
  const u16* xr = xbf + (size_t)n * 16;
  {  // U1 row -> LDS: [sums20, x(n)16, 0..]; lane q writes elems q*4..q*4+3
    u32 w2[2];
#pragma unroll
    for (int jj = 0; jj < 2; ++jj) {
      int t0 = q * 4 + 2 * jj, t1 = t0 + 1;
      u16 b0 = (t0 < 20) ? f2bf(v[t0]) : ((t0 < 36 && nval) ? xr[t0 - 20] : (u16)0);
      u16 b1 = (t1 < 20) ? f2bf(v[t1]) : ((t1 < 36 && nval) ? xr[t1 - 20] : (u16)0);
      w2[jj] = (u32)b0 | ((u32)b1 << 16);
    }
    *(uint2*)&Uls[nl][q * 4] = make_uint2(w2[0], w2[1]);
  }
  if (nval) {  // acc1c row: [sx16, sea4, deg, 0..]; lane q -> elems 2q,2q+1
    int t0 = q * 2, t1 = t0 + 1;
    float f0 = (t0 < 20) ? v[t0] : ((t0 == 20) ? degf : 0.f);
    float f1 = (t1 < 20) ? v[t1] : ((t1 == 20) ? degf : 0.f);
    *(u32*)(acc1c + (size_t)n * 32 + q * 2) = (u32)f2bf(f0) | ((u32)f2bf(f1) << 16);
  }
  if (q == 0) degls[nl] = degf;
  __syncthreads();
  // Phase B: 12 n-tile jobs over 4 waves; h1 raw pooling fused (f = 208+col)
  int w = tid >> 6, lane = tid & 63, rc = lane & 15, qd = lane >> 4;
  int slice = (blockIdx.x & 63) * 384;
  for (int nt = w; nt < 12; nt += 4) {
    f32x4 acc = {0.f, 0.f, 0.f, 0.f};
#pragma unroll
    for (int kb = 0; kb < 2; ++kb) {
      short8 av = *(const short8*)&Uls[rc][kb * 32 + qd * 8];
      short8 bv = *(const short8*)(Bp + (size_t)((kb * 4 + qd) * 192 + nt * 16 + rc) * 8);
      acc = __builtin_amdgcn_mfma_f32_16x16x32_bf16(av, bv, acc, 0, 0, 0);
    }
    int col = nt * 16 + rc;
    float bb = bm1[col] + be1[col], bsv = bs1[col];
    float ps = 0.f, pq = 0.f;
    float sl = 0.f, mxl = -3.4e38f, mnl = 3.4e38f;
    float vv[4];
#pragma unroll
    for (int r = 0; r < 4; ++r) {
      int ml = qd * 4 + r;
      int m = blockIdx.x * 16 + ml;
      float val = acc[r] + degls[ml] * bb + bsv;
      u16 vb = f2bf(val);
      float vr = bf2f(vb);  // pooled value = bf16-rounded (matches h1bf read)
      vv[r] = vr;
      if (m < N) {
        h1bf[(size_t)m * 192 + col] = vb;
        ps += val;
        pq += val * val;
        sl += vr;
        mxl = fmaxf(mxl, vr);
        mnl = fminf(mnl, vr);
      }
    }
    ps += __shfl_xor(ps, 16); ps += __shfl_xor(ps, 32);
    pq += __shfl_xor(pq, 16); pq += __shfl_xor(pq, 32);
    if (uni) {
      sl += __shfl_xor(sl, 16); sl += __shfl_xor(sl, 32);
      mxl = fmaxf(mxl, __shfl_xor(mxl, 16)); mxl = fmaxf(mxl, __shfl_xor(mxl, 32));
      mnl = fminf(mnl, __shfl_xor(mnl, 16)); mnl = fminf(mnl, __shfl_xor(mnl, 32));
    }
    if (qd == 0) {
      atomAddF(&bns1p[slice + col], ps);
      atomAddF(&bns1p[slice + 192 + col], pq);
      if (uni) {
        int pidx = gid_lo * 416 + 208 + col;
        atomAddF(&psumg[pidx], sl);
        atomicMax(&pmaxg[pidx], encf(mxl));
        atomicMin(&pming[pidx], encf(mnl));
      }
    }
    if (!uni) {  // boundary block: per-run atomics over this lane's 4 rows
      int cg = -1;
      float rs = 0.f, rmx = -3.4e38f, rmn = 3.4e38f;
#pragma unroll
      for (int r = 0; r < 4; ++r) {
        int m = blockIdx.x * 16 + qd * 4 + r;
        if (m >= N) continue;
        int g = batch[m];
        if (g != cg) {
          if (cg >= 0) {
            int pidx = cg * 416 + 208 + col;
            atomAddF(&psumg[pidx], rs);
            atomicMax(&pmaxg[pidx], encf(rmx));
            atomicMin(&pming[pidx], encf(rmn));
          }
          cg = g; rs = 0.f; rmx = -3.4e38f; rmn = 3.4e38f;
        }
        rs += vv[r];
        rmx = fmaxf(rmx, vv[r]);
        rmn = fminf(rmn, vv[r]);
      }
      if (cg >= 0) {
        int pidx = cg * 416 + 208 + col;
        atomAddF(&psumg[pidx], rs);
        atomicMax(&pmaxg[pidx], encf(rmx));
        atomicMin(&pming[pidx], encf(rmn));
      }
    }
  }
  // ---- pool x from Uls cols 20..35 (raw): -> global feature 400+c, c in [0,16) ----
  if (tid < 16) {
    int c = tid;
    int rows = min(16, N - base);
    if (uni) {
      float s = 0.f, mx = -3.4e38f, mn = 3.4e38f;
      for (int ml = 0; ml < rows; ++ml) {
        float vx = bf2f(Uls[ml][20 + c]);
        s += vx;
        mx = fmaxf(mx, vx);
        mn = fminf(mn, vx);
      }
      int pidx = gid_lo * 416 + 400 + c;
      atomAddF(&psumg[pidx], s);
      atomicMax(&pmaxg[pidx], encf(mx));
      atomicMin(&pming[pidx], encf(mn));
    } else {
      int cg = -1;
      float rs = 0.f, rmx = -3.4e38f, rmn = 3.4e38f;
      for (int ml = 0; ml < rows; ++ml) {
        int g = batch[base + ml];
        if (g != cg) {
          if (cg >= 0) {
            int pidx = cg * 416 + 400 + c;
            atomAddF(&psumg[pidx], rs);
            atomicMax(&pmaxg[pidx], encf(rmx));
            atomicMin(&pming[pidx], encf(rmn));
          }
          cg = g; rs = 0.f; rmx = -3.4e38f; rmn = 3.4e38f;
        }
        float vx = bf2f(Uls[ml][20 + c]);
        rs += vx;
        rmx = fmaxf(rmx, vx);
        rmn = fminf(rmn, vx);
      }
      if (cg >= 0) {
        int pidx = cg * 416 + 400 + c;
        atomAddF(&psumg[pidx], rs);
        atomicMax(&pmaxg[pidx], encf(rmx));
        atomicMin(&pming[pidx], encf(rmn));
      }
    }
  }
}

// ---- bn1 finalize ---- 1 block, 256 threads
__global__ void bnfin1_k(const float* __restrict__ bns1p, const float* __restrict__ g1,
                         const float* __restrict__ bta1, float Ninv,
                         float* __restrict__ aff1) {
  int c = threadIdx.x;
  if (c >= 192) return;
  float sm = 0.f, sq = 0.f;
  for (int k = 0; k < 64; ++k) {
    sm += bns1p[k * 384 + c];
    sq += bns1p[k * 384 + 192 + c];
  }
  float m1 = sm * Ninv;
  float var = sq * Ninv - m1 * m1;
  float s1 = g1[c] * rsqrtf(var + 1e-5f);
  aff1[c] = s1;
  aff1[192 + c] = bta1[c] - m1 * s1;
}

// ---- CONV2: gather2 + U2 + X1 staged + gemms + bn2 stats + h2 RAW POOLING only ----
// grid ceil(N/16), block 256 (4 waves). h2 never materialized.
__global__ void __launch_bounds__(256) conv2_k(
    const int4* __restrict__ se16, const int* __restrict__ rowptr,
    const u16* __restrict__ acc1c, const u16* __restrict__ h1bf,
    const u16* __restrict__ xbf, const u16* __restrict__ Bp1, const u16* __restrict__ Bp2,
    const float* __restrict__ bm1, const float* __restrict__ be1,
    const float* __restrict__ bs1, const float* __restrict__ aff1,
    const float* __restrict__ We2, const float* __restrict__ bm2,
    const float* __restrict__ be2, float* __restrict__ bns2p,
    const int* __restrict__ batch, float* __restrict__ psumg,
    u32* __restrict__ pmaxg, u32* __restrict__ pming, int N) {
  __shared__ __align__(16) u16 Uls[16][72];
  __shared__ __align__(16) u16 Vls[16][232];
  __shared__ __align__(16) u16 X1ls[16][208];  // cols 0..191 h1 raw, 192..207 x raw
  __shared__ float degls[16], sdegls[16], eals[16][4];
  int tid = threadIdx.x;
  int nl = tid >> 4, q = tid & 15;
  int n = blockIdx.x * 16 + nl;
  bool nval = n < N;
  int j0 = nval ? rowptr[n] : 0;
  int j1 = nval ? rowptr[n + 1] : 0;
  int base = blockIdx.x * 16;
  int gid_lo = batch[base];
  int gid_hi = batch[min(base + 15, N - 1)];
  bool uni = (gid_lo == gid_hi);

  // ---- stage X1 rows: issue coalesced loads first (overlap with gather) ----
  uint4 sg0, sg1, sgx;
  int r0 = tid / 24, c0 = tid % 24;                 // rows 0..10
  int r1 = (tid + 256) / 24, c1 = (tid + 256) % 24; // rows 10..15 (tid<128)
  {
    int gr = base + r0;
    sg0 = (gr < N) ? *(const uint4*)(h1bf + (size_t)gr * 192 + c0 * 8)
                   : make_uint4(0, 0, 0, 0);
  }
  if (tid < 128) {
    int gr = base + r1;
    sg1 = (gr < N) ? *(const uint4*)(h1bf + (size_t)gr * 192 + c1 * 8)
                   : make_uint4(0, 0, 0, 0);
  }
  if (tid < 32) {
    int gr = base + (tid >> 1);
    sgx = (gr < N) ? *(const uint4*)(xbf + (size_t)gr * 16 + (tid & 1) * 8)
                   : make_uint4(0, 0, 0, 0);
  }

  float v[21];
#pragma unroll
  for (int i = 0; i < 21; ++i) v[i] = 0.f;
  {
    // Unrolled 2-deep gather prefetch (see conv1_k).
    int j = j0 + q;
    bool a0 = j < j1, a1 = (j + 16) < j1;
    int jj0 = a0 ? j : 0;
    int jj1 = a1 ? (j + 16) : 0;
    int4 p0 = se16[jj0];
    int4 p1 = se16[jj1];
    const uint4* cr0 = (const uint4*)(acc1c + (size_t)(a0 ? p0.x : 0) * 32);
    uint4 c00 = cr0[0], c01 = cr0[1], c02 = cr0[2];
    const uint4* cr1 = (const uint4*)(acc1c + (size_t)(a1 ? p1.x : 0) * 32);
    uint4 c10 = cr1[0], c11 = cr1[1], c12 = cr1[2];
    if (a0) {
      addp(v + 0, c00.x); addp(v + 2, c00.y); addp(v + 4, c00.z); addp(v + 6, c00.w);
      addp(v + 8, c01.x); addp(v + 10, c01.y); addp(v + 12, c01.z); addp(v + 14, c01.w);
      addp(v + 16, c02.x); addp(v + 18, c02.y);
      v[20] += bf2f((u16)c02.z);
    }
    if (a1) {
      addp(v + 0, c10.x); addp(v + 2, c10.y); addp(v + 4, c10.z); addp(v + 6, c10.w);
      addp(v + 8, c11.x); addp(v + 10, c11.y); addp(v + 12, c11.z); addp(v + 14, c11.w);
      addp(v + 16, c12.x); addp(v + 18, c12.y);
      v[20] += bf2f((u16)c12.z);
    }
    for (j += 32; j < j1; j += 16) {  // rare tail (deg > 32)
      int s = se16[j].x;
      const uint4* cr = (const uint4*)(acc1c + (size_t)s * 32);
      uint4 c0 = cr[0], c1 = cr[1], c2 = cr[2];
      addp(v + 0, c0.x); addp(v + 2, c0.y); addp(v + 4, c0.z); addp(v + 6, c0.w);
      addp(v + 8, c1.x); addp(v + 10, c1.y); addp(v + 12, c1.z); addp(v + 14, c1.w);
      addp(v + 16, c2.x); addp(v + 18, c2.y);
      v[20] += bf2f((u16)c2.z);
    }
  }

  // ---- write staged X1 rows to LDS (loads had gather-time to land) ----
  *(uint4*)&X1ls[r0][c0 * 8] = sg0;
  if (tid < 128) *(uint4*)&X1ls[r1][c1 * 8] = sg1;
  if (tid < 32) *(uint4*)&X1ls[tid >> 1][192 + (tid & 1) * 8] = sgx;

#pragma unroll
  for (int i = 0; i < 21; ++i) {
    v[i] += __shfl_xor(v[i], 1);
    v[i] += __shfl_xor(v[i], 2);
    v[i] += __shfl_xor(v[i], 4);
    v[i] += __shfl_xor(v[i], 8);
  }
  const u16* selfr = acc1c + (size_t)n * 32;
  {  // U2 row -> LDS: [sums20, self sx16, 0..]; lane q writes elems q*4..q*4+3
    u32 w2[2];
#pragma unroll
    for (int jj = 0; jj < 2; ++jj) {
      int t0 = q * 4 + 2 * jj, t1 = t0 + 1;
      u16 b0 = (t0 < 20) ? f2bf(v[t0]) : ((t0 < 36 && nval) ? selfr[t0 - 20] : (u16)0);
      u16 b1 = (t1 < 20) ? f2bf(v[t1]) : ((t1 < 36 && nval) ? selfr[t1 - 20] : (u16)0);
      w2[jj] = (u32)b0 | ((u32)b1 << 16);
    }
    *(uint2*)&Uls[nl][q * 4] = make_uint2(w2[0], w2[1]);
  }
  {  // V tail cols [192..224): self sx16 then zeros; lane q -> elems 192+2q, +1
    int t0 = q * 2, t1 = t0 + 1;
    u16 b0 = (t0 < 16 && nval) ? selfr[t0] : (u16)0;
    u16 b1 = (t1 < 16 && nval) ? selfr[t1] : (u16)0;
    *(u32*)&Vls[nl][192 + q * 2] = (u32)b0 | ((u32)b1 << 16);
  }
  if (q == 0) sdegls[nl] = v[20];
  if (q == 1) degls[nl] = nval ? bf2f(selfr[20]) : 0.f;
  if (q == 2) {
#pragma unroll
    for (int k = 0; k < 4; ++k) eals[nl][k] = nval ? bf2f(selfr[16 + k]) : 0.f;
  }
  __syncthreads();
  // Phase B: gemmq2 -> Vls[:,0..192), 12 jobs / 4 waves
  int w = tid >> 6, lane = tid & 63, rc = lane & 15, qd = lane >> 4;
  for (int nt = w; nt < 12; nt += 4) {
    f32x4 acc = {0.f, 0.f, 0.f, 0.f};
#pragma unroll
    for (int kb = 0; kb < 2; ++kb) {
      short8 av = *(const short8*)&Uls[rc][kb * 32 + qd * 8];
      short8 bv = *(const short8*)(Bp1 + (size_t)((kb * 4 + qd) * 192 + nt * 16 + rc) * 8);
      acc = __builtin_amdgcn_mfma_f32_16x16x32_bf16(av, bv, acc, 0, 0, 0);
    }
    int col = nt * 16 + rc;
    float s1 = aff1[col], t1 = aff1[192 + col];
    float bb = bm1[col] + be1[col], bsv = bs1[col];
#pragma unroll
    for (int r = 0; r < 4; ++r) {
      int ml = qd * 4 + r;
      float qv = acc[r] + sdegls[ml] * bb + degls[ml] * bsv;
      Vls[ml][col] = f2bf(qv * s1 + degls[ml] * t1);
    }
  }
  __syncthreads();
  // Phase C: gemm2 + bn2 stats + h2 pooling (raw); NO h2 store at all.
  int slice = (blockIdx.x & 63) * 832;
  for (int nt = w; nt < 13; nt += 4) {
    f32x4 acc = {0.f, 0.f, 0.f, 0.f};
#pragma unroll
    for (int kb = 0; kb < 7; ++kb) {
      short8 av = *(const short8*)&Vls[rc][kb * 32 + qd * 8];
      short8 bv = *(const short8*)(Bp2 + (size_t)((kb * 4 + qd) * 208 + nt * 16 + rc) * 8);
      acc = __builtin_amdgcn_mfma_f32_16x16x32_bf16(av, bv, acc, 0, 0, 0);
    }
    int col = nt * 16 + rc;
    float w0 = We2[col], w1 = We2[208 + col], w2 = We2[416 + col], w3 = We2[624 + col];
    float bb2 = bm2[col] + be2[col];
    bool c192 = col < 192;
    float s1 = c192 ? aff1[col] : 0.f;
    float t1 = c192 ? aff1[192 + col] : 0.f;
    float ps = 0.f, pq = 0.f;
    float sl = 0.f, mxl = -3.4e38f, mnl = 3.4e38f;
    float vv[4];
#pragma unroll
    for (int r = 0; r < 4; ++r) {
      int ml = qd * 4 + r;
      int m = blockIdx.x * 16 + ml;
      bool mv = m < N;
      float x1 = bf2f(X1ls[ml][col]);
      if (c192) x1 = x1 * s1 + t1;
      float val = acc[r] + eals[ml][0] * w0 + eals[ml][1] * w1 + eals[ml][2] * w2 +
                  eals[ml][3] * w3 + degls[ml] * bb2 + x1;
      vv[r] = val;
      if (mv) {
        ps += val;
        pq += val * val;
        sl += val;
        mxl = fmaxf(mxl, val);
        mnl = fminf(mnl, val);
      }
    }
    ps += __shfl_xor(ps, 16); ps += __shfl_xor(ps, 32);
    pq += __shfl_xor(pq, 16); pq += __shfl_xor(pq, 32);
    if (uni) {
      sl += __shfl_xor(sl, 16); sl += __shfl_xor(sl, 32);
      mxl = fmaxf(mxl, __shfl_xor(mxl, 16)); mxl = fmaxf(mxl, __shfl_xor(mxl, 32));
      mnl = fminf(mnl, __shfl_xor(mnl, 16)); mnl = fminf(mnl, __shfl_xor(mnl, 32));
    }
    if (qd == 0) {
      atomAddF(&bns2p[slice + col], ps);
      atomAddF(&bns2p[slice + 416 + col], pq);
      if (uni) {
        int pidx = gid_lo * 416 + col;
        atomAddF(&psumg[pidx], sl);
        atomicMax(&pmaxg[pidx], encf(mxl));
        atomicMin(&pming[pidx], encf(mnl));
      }
    }
    if (!uni) {  // boundary block (~4%): per-run atomics over this lane's 4 rows
      int cg = -1;
      float rs = 0.f, rmx = -3.4e38f, rmn = 3.4e38f;
#pragma unroll
      for (int r = 0; r < 4; ++r) {
        int m = blockIdx.x * 16 + qd * 4 + r;
        if (m >= N) continue;
        int g = batch[m];
        if (g != cg) {
          if (cg >= 0) {
            int pidx = cg * 416 + col;
            atomAddF(&psumg[pidx], rs);
            atomicMax(&pmaxg[pidx], encf(rmx));
            atomicMin(&pming[pidx], encf(rmn));
          }
          cg = g; rs = 0.f; rmx = -3.4e38f; rmn = 3.4e38f;
        }
        rs += vv[r];
        rmx = fmaxf(rmx, vv[r]);
        rmn = fminf(rmn, vv[r]);
      }
      if (cg >= 0) {
        int pidx = cg * 416 + col;
        atomAddF(&psumg[pidx], rs);
        atomicMax(&pmaxg[pidx], encf(rmx));
        atomicMin(&pming[pidx], encf(rmn));
      }
    }
  }
}

// ---- pooled finalize: bn affines + sum/max/mean -> bf16 A [64 x 1248] ---- grid=64
__global__ void pooledprep_k(const float* __restrict__ psumg, const u32* __restrict__ pmaxg,
                             const u32* __restrict__ pming,
                             const int* __restrict__ gstart, const int* __restrict__ gend,
                             const float* __restrict__ bns2p, const float* __restrict__ aff1,
                             const float* __restrict__ g2, const float* __restrict__ bta2,
                             float Ninv, u16* __restrict__ Apool) {
  __shared__ float scs[416], shs[416];
  int b = blockIdx.x, t = threadIdx.x;
  for (int f = t; f < 416; f += 256) {
    float sc, sh;
    if (f < 208) {
      float sm = 0.f, sq = 0.f;
      for (int k = 0; k < 64; ++k) {
        sm += bns2p[k * 832 + f];
        sq += bns2p[k * 832 + 416 + f];
      }
      float m2 = sm * Ninv;
      float var = sq * Ninv - m2 * m2;
      sc = g2[f] * rsqrtf(var + 1e-5f);
      sh = bta2[f] - m2 * sc;
    } else if (f < 400) {
      sc = aff1[f - 208];
      sh = aff1[192 + (f - 208)];
    } else {
      sc = 1.f;
      sh = 0.f;
    }
    scs[f] = sc;
    shs[f] = sh;
  }
  __syncthreads();
  int cnt = gend[b] - gstart[b] + 1;
  float inv = 1.f / (float)max(cnt, 1);
  for (int f = t; f < 416; f += 256) {
    float s = psumg[b * 416 + f];
    float mx = decf(pmaxg[b * 416 + f]);
    float mn = decf(pming[b * 416 + f]);
    float sc = scs[f], sh = shs[f];
    float sumf = sc * s + (float)cnt * sh;  // affine-commuted sum
    float mxf = (sc >= 0.f) ? sc * mx + sh : sc * mn + sh;
    u16* row = Apool + (size_t)b * 1248;
    row[f] = f2bf(sumf);
    row[416 + f] = f2bf((cnt > 0) ? mxf : 0.f);
    row[832 + f] = f2bf(sumf * inv);
  }
}

// ---- MLP layer 1 via MFMA, K split over 4 waves + LDS reduce ---- grid=(4,39), 256
__global__ void __launch_bounds__(256) mlpgemm_k(const u16* __restrict__ A,
                                                 const u16* __restrict__ Bp,
                                                 const float* __restrict__ b1,
                                                 const float* __restrict__ al,
                                                 float* __restrict__ hid) {
  __shared__ __align__(16) float part[3][64][4];
  int tid = threadIdx.x;
  int w = tid >> 6, lane = tid & 63;
  int mt = blockIdx.x, nt = blockIdx.y;
  int rc = lane & 15, qd = lane >> 4;
  f32x4 acc = {0.f, 0.f, 0.f, 0.f};
  const u16* Ap = A + (size_t)(mt * 16 + rc) * 1248 + qd * 8;
  const u16* Bq = Bp + (size_t)(qd * 624 + nt * 16 + rc) * 8;
  for (int kb = w; kb < 39; kb += 4) {
    short8 av = *(const short8*)(Ap + kb * 32);
    short8 bv = *(const short8*)(Bq + (size_t)kb * 4 * 624 * 8);
    acc = __builtin_amdgcn_mfma_f32_16x16x32_bf16(av, bv, acc, 0, 0, 0);
  }
  if (w > 0) *(f32x4*)&part[w - 1][lane][0] = acc;
  __syncthreads();
  if (w == 0) {
#pragma unroll
    for (int j = 0; j < 3; ++j) {
      f32x4 p = *(const f32x4*)&part[j][lane][0];
      acc[0] += p[0]; acc[1] += p[1]; acc[2] += p[2]; acc[3] += p[3];
    }
    int col = nt * 16 + rc;
    float bb = b1[col], alpha = al[0];
    int m0 = mt * 16 + qd * 4;
#pragma unroll
    for (int r = 0; r < 4; ++r) {
      float v = acc[r] + bb;
      hid[(size_t)(m0 + r) * 624 + col] = (v >= 0.f) ? v : alpha * v;
    }
  }
}

// ---- logits + log_softmax ---- grid=64, block=64
__global__ void head_k(const float* __restrict__ hid, const float* __restrict__ W2,
                       const float* __restrict__ b2, float* __restrict__ out) {
  int b = blockIdx.x, t = threadIdx.x;
  float p0 = 0.f, p1 = 0.f;
  for (int k = t; k < 624; k += 64) {
    float h = hid[(size_t)b * 624 + k];
    p0 += h * W2[k * 2];
    p1 += h * W2[k * 2 + 1];
  }
#pragma unroll
  for (int off = 32; off > 0; off >>= 1) {
    p0 += __shfl_down(p0, off);
    p1 += __shfl_down(p1, off);
  }
  if (t == 0) {
    float l0 = p0 + b2[0], l1 = p1 + b2[1];
    float m = fmaxf(l0, l1);
    float lse = m + logf(expf(l0 - m) + expf(l1 - m));
    out[b * 2] = l0 - lse;
    out[b * 2 + 1] = l1 - lse;
  }
}

extern "C" void kernel_launch(void* const* d_in, const int* in_sizes, int n_in,
                              void* d_out, int out_size, void* d_ws, size_t ws_size,
                              hipStream_t stream) {
  const float* x = (const float*)d_in[0];
  const int* ei = (const int*)d_in[1];
  const float* ea = (const float*)d_in[2];
  const int* batch = (const int*)d_in[3];
  const float* Wm1 = (const float*)d_in[4];
  const float* bm1 = (const float*)d_in[5];
  const float* We1 = (const float*)d_in[6];
  const float* be1 = (const float*)d_in[7];
  const float* Ws1 = (const float*)d_in[8];
  const float* bs1 = (const float*)d_in[9];
  const float* g1 = (const float*)d_in[10];
  const float* bta1 = (const float*)d_in[11];
  const float* Wm2 = (const float*)d_in[12];
  const float* bm2 = (const float*)d_in[13];
  const float* We2 = (const float*)d_in[14];
  const float* be2 = (const float*)d_in[15];
  const float* g2 = (const float*)d_in[16];
  const float* bta2 = (const float*)d_in[17];
  const float* Wl1 = (const float*)d_in[18];
  const float* bl1 = (const float*)d_in[19];
  const float* alpha = (const float*)d_in[20];
  const float* Wl2 = (const float*)d_in[21];
  const float* bl2 = (const float*)d_in[22];
  float* out = (float*)d_out;

  const int N = in_sizes[3];      // 50000
  const int E = in_sizes[2] / 4;  // 800000
  const int nb = (N + 255) / 256; // 196 (<=256)
  const float Ninv = 1.f / (float)N;

  float* ws = (float*)d_ws;
  size_t o = 0;
  u16* acc1c = (u16*)(ws + o); o += (size_t)N * 16;  // N*32 u16
  u16* h1bf = (u16*)(ws + o);  o += (size_t)N * 96;  // N*192 u16
  u16* xbf = (u16*)(ws + o);   o += (size_t)N * 8;   // N*16 u16
  u16* Wp1 = (u16*)(ws + o);   o += 6144;
  u16* Wp2 = (u16*)(ws + o);   o += 23296;
  u16* Wp3 = (u16*)(ws + o);   o += 389376;
  u16* Apool = (u16*)(ws + o); o += 39936;
  float* hid = ws + o;    o += 64 * 624;
  float* bns1p = ws + o;  o += 64 * 384;
  float* bns2p = ws + o;  o += 64 * 832;
  float* aff1 = ws + o;   o += 384;
  float* psumg = ws + o;  o += 64 * 416;
  u32* pmaxg = (u32*)(ws + o); o += 64 * 416;
  u32* pming = (u32*)(ws + o); o += 64 * 416;
  int* gstart = (int*)(ws + o); o += 64;
  int* gend = (int*)(ws + o);   o += 64;
  int* deg = (int*)(ws + o);    o += N;
  int* rowptr = (int*)(ws + o); o += N + 1;
  int* ord = (int*)(ws + o);    o += E;
  int* bsum = (int*)(ws + o);   o += 256;
  o = (o + 3) & ~(size_t)3;  // 16B align for int4
  int4* se16 = (int4*)(ws + o); o += (size_t)4 * E;

  const int gconv = (N + 15) / 16;  // 3125
  prep_k<<<(E + 255) / 256, 256, 0, stream>>>(Wm1, We1, Ws1, Wm2, Wl1, x, batch, Wp1, Wp2,
                                              Wp3, xbf, gstart, gend, deg, bns1p, bns2p,
                                              psumg, pmaxg, pming, N, E);
  count_k<<<(E + 255) / 256, 256, 0, stream>>>(ei, deg, ord, E);
  scanA_k<<<nb, 256, 0, stream>>>(deg, bsum, N);
  scanC_k<<<nb, 256, 0, stream>>>(deg, bsum, rowptr, N, nb);
  scatter_k<<<(E + 255) / 256, 256, 0, stream>>>(ei, ea, ord, rowptr, se16, E);
  conv1_k<<<gconv, 256, 0, stream>>>(se16, rowptr, xbf, Wp1, bm1, be1, bs1, acc1c, h1bf,
                                     bns1p, batch, psumg, pmaxg, pming, N);
  bnfin1_k<<<1, 256, 0, stream>>>(bns1p, g1, bta1, Ninv, aff1);
  conv2_k<<<gconv, 256, 0, stream>>>(se16, rowptr, acc1c, h1bf, xbf, Wp1, Wp2, bm1, be1,
                                     bs1, aff1, We2, bm2, be2, bns2p, batch, psumg,
                                     pmaxg, pming, N);
  pooledprep_k<<<64, 256, 0, stream>>>(psumg, pmaxg, pming, gstart, gend, bns2p, aff1,
                                       g2, bta2, Ninv, Apool);
  mlpgemm_k<<<dim3(4, 39), 256, 0, stream>>>(Apool, Wp3, bl1, alpha, hid);
  head_k<<<64, 64, 0, stream>>>(hid, Wl2, bl2, out);
}